// Round 1
// baseline (3870.498 us; speedup 1.0000x reference)
//
#include <hip/hip_runtime.h>

namespace {

constexpr int B_   = 16;
constexpr int T_   = 8;
constexpr int C_   = 16;
constexpr int HW   = 64 * 64;            // 4096
constexpr int SBS  = 64 * HW;            // seq0 per-batch stride (64 channels)
constexpr long B64HW = (long)B_ * 64 * HW; // per-time block in seq0

__device__ __forceinline__ float sigm(float x)  { return 1.0f / (1.0f + __expf(-x)); }
__device__ __forceinline__ float ftanh(float x) { return 1.0f - 2.0f / (1.0f + __expf(2.0f * x)); }

// [CO][CIN*9] -> [CIN*9][CO] transpose so conv inner loop reads contiguous per-(ci,dy,dx) co-rows
__global__ void wtrans_kernel(const float* __restrict__ w, float* __restrict__ wt,
                              int CO, int R) {
  int i = blockIdx.x * 256 + threadIdx.x;
  if (i >= CO * R) return;
  int co = i / R, r = i - co * R;
  wt[r * CO + co] = w[i];
}

// xs = x_audio + tanh(relu(notes@w1+b1)@w2+b2), layout [B,T,C,H,W]
__global__ void pe_add_kernel(const float* __restrict__ xa, const float* __restrict__ midi,
                              const float* __restrict__ w1, const float* __restrict__ b1,
                              const float* __restrict__ w2, const float* __restrict__ b2,
                              float* __restrict__ xs) {
  constexpr int PE = C_ * HW; // 65536
  int idx = blockIdx.x * 256 + threadIdx.x;   // total = B*T*PE, divisible by 256
  int bt = idx >> 16;
  int p  = idx & 65535;
  float n0 = -0.5f + midi[bt * 2 + 0] * (1.0f / 64.0f);
  float n1 = -0.5f + midi[bt * 2 + 1] * (1.0f / 64.0f);
  float z = b2[p];
#pragma unroll
  for (int k = 0; k < 4; ++k) {
    float h = fmaf(n0, w1[k], fmaf(n1, w1[4 + k], b1[k]));
    h = fmaxf(h, 0.0f);
    z = fmaf(h, w2[k * PE + p], z);
  }
  xs[idx] = xa[idx] + ftanh(z);
}

// Generic ConvLSTM step / plain conv.
// Input channels: ci < CIN1 from x_in, ci >= CIN1 from h_in (nullptr => zeros).
// GATES: COUT=128 (i,f,o,g per 32 hid ch); block owns 8 hid ch (blockIdx.y in [0,4)).
// !GATES: block owns 32 of COUT output channels (blockIdx.y in [0,COUT/32)).
template<int CIN1, bool GATES, int COUT>
__global__ __launch_bounds__(256)
void conv_step(const float* __restrict__ x_in, int x_bs,
               const float* __restrict__ h_in, int h_bs,
               const float* __restrict__ wt, const float* __restrict__ bias,
               const float* __restrict__ c_in, float* __restrict__ c_out,
               float* __restrict__ h_out, int hout_bs,
               int cin_loop)
{
  constexpr int ROWS = 4, CIC = 16;
  constexpr int STG = CIC * (ROWS + 2) * 66;  // 6336
  __shared__ float lds[CIC][ROWS + 2][66];
  const int tid = threadIdx.x;
  const int xl = tid & 63, yl = tid >> 6;
  const int y0 = blockIdx.x * ROWS;
  const int cb = blockIdx.y;
  const int b  = blockIdx.z;

  float acc[4][8];
#pragma unroll
  for (int g = 0; g < 4; ++g)
#pragma unroll
    for (int k = 0; k < 8; ++k) acc[g][k] = 0.0f;

  for (int ci0 = 0; ci0 < cin_loop; ci0 += CIC) {
    __syncthreads();
    for (int i = tid; i < STG; i += 256) {
      int cil = i / 396;
      int rem = i - cil * 396;
      int ry  = rem / 66;
      int cx  = rem - ry * 66;
      int gy = y0 - 1 + ry, gx = cx - 1;
      float v = 0.0f;
      int cig = ci0 + cil;
      if ((unsigned)gy < 64u && (unsigned)gx < 64u) {
        if (cig < CIN1)   v = x_in[b * x_bs + cig * HW + gy * 64 + gx];
        else if (h_in)    v = h_in[b * h_bs + (cig - CIN1) * HW + gy * 64 + gx];
      }
      (&lds[0][0][0])[i] = v;
    }
    __syncthreads();
    for (int ci = 0; ci < CIC; ++ci) {
      const float* wb = wt + (ci0 + ci) * 9 * COUT;
#pragma unroll
      for (int dy = 0; dy < 3; ++dy) {
        const float v0 = lds[ci][yl + dy][xl];
        const float v1 = lds[ci][yl + dy][xl + 1];
        const float v2 = lds[ci][yl + dy][xl + 2];
        const float* w = wb + dy * 3 * COUT;
#pragma unroll
        for (int g = 0; g < 4; ++g) {
#pragma unroll
          for (int k = 0; k < 8; ++k) {
            const int co = GATES ? (g * 32 + cb * 8 + k) : (cb * 32 + g * 8 + k);
            float a = acc[g][k];
            a = fmaf(w[co],            v0, a);
            a = fmaf(w[COUT + co],     v1, a);
            a = fmaf(w[2 * COUT + co], v2, a);
            acc[g][k] = a;
          }
        }
      }
    }
  }

  const int y = y0 + yl;
  const int pix = y * 64 + xl;
  if constexpr (GATES) {
#pragma unroll
    for (int k = 0; k < 8; ++k) {
      const int hc = cb * 8 + k;
      float zi = acc[0][k] + bias[hc];
      float zf = acc[1][k] + bias[32 + hc];
      float zo = acc[2][k] + bias[64 + hc];
      float zg = acc[3][k] + bias[96 + hc];
      const int cidx = ((b * 32 + hc) << 12) + pix;
      float cp = c_in ? c_in[cidx] : 0.0f;
      float c2 = sigm(zf) * cp + sigm(zi) * ftanh(zg);
      float h2 = sigm(zo) * ftanh(c2);
      c_out[cidx] = c2;
      h_out[b * hout_bs + (hc << 12) + pix] = h2;
    }
  } else {
#pragma unroll
    for (int g = 0; g < 4; ++g)
#pragma unroll
      for (int k = 0; k < 8; ++k) {
        const int co = cb * 32 + g * 8 + k;
        h_out[b * hout_bs + (co << 12) + pix] = acc[g][k] + bias[co];
      }
  }
}

} // namespace

extern "C" void kernel_launch(void* const* d_in, const int* in_sizes, int n_in,
                              void* d_out, int out_size, void* d_ws, size_t ws_size,
                              hipStream_t stream) {
  const float* x_audio = (const float*)d_in[0];
  const float* midi    = (const float*)d_in[1];
  const float* enc_w1  = (const float*)d_in[2];
  const float* enc_b1  = (const float*)d_in[3];
  const float* enc_w2  = (const float*)d_in[4];
  const float* enc_b2  = (const float*)d_in[5];
  const float* w0f = (const float*)d_in[6];
  const float* b0f = (const float*)d_in[7];
  const float* w0b = (const float*)d_in[8];
  const float* b0b = (const float*)d_in[9];
  const float* w1f = (const float*)d_in[10];
  const float* b1f = (const float*)d_in[11];
  const float* w1b = (const float*)d_in[12];
  const float* b1b = (const float*)d_in[13];
  const float* fcw = (const float*)d_in[14];
  const float* fcb = (const float*)d_in[15];
  float* out = (float*)d_out;

  float* p = (float*)d_ws;
  float* xs   = p; p += (size_t)B_ * T_ * C_ * HW;  // 8,388,608
  float* seq0 = p; p += (size_t)T_ * B_ * 64 * HW;  // 33,554,432  [T][B][64][HW]
  float* c0f  = p; p += (size_t)B_ * 32 * HW;
  float* c0b  = p; p += (size_t)B_ * 32 * HW;
  float* h1p0 = p; p += (size_t)B_ * 32 * HW;
  float* h1p1 = p; p += (size_t)B_ * 32 * HW;
  float* c1f  = p; p += (size_t)B_ * 32 * HW;
  float* h1bw = p; p += (size_t)B_ * 32 * HW;
  float* c1bw = p; p += (size_t)B_ * 32 * HW;
  float* wt0f = p; p += 48 * 9 * 128;
  float* wt0b = p; p += 48 * 9 * 128;
  float* wt1f = p; p += 96 * 9 * 128;
  float* wt1b = p; p += 96 * 9 * 128;
  float* wtfc = p; p += 64 * 9 * 64;

  // weight transposes
  {
    int n;
    n = 128 * 48 * 9; wtrans_kernel<<<(n + 255) / 256, 256, 0, stream>>>(w0f, wt0f, 128, 48 * 9);
    n = 128 * 48 * 9; wtrans_kernel<<<(n + 255) / 256, 256, 0, stream>>>(w0b, wt0b, 128, 48 * 9);
    n = 128 * 96 * 9; wtrans_kernel<<<(n + 255) / 256, 256, 0, stream>>>(w1f, wt1f, 128, 96 * 9);
    n = 128 * 96 * 9; wtrans_kernel<<<(n + 255) / 256, 256, 0, stream>>>(w1b, wt1b, 128, 96 * 9);
    n = 64 * 64 * 9;  wtrans_kernel<<<(n + 255) / 256, 256, 0, stream>>>(fcw, wtfc, 64, 64 * 9);
  }

  // positional encoding + add
  pe_add_kernel<<<(B_ * T_ * C_ * HW) / 256, 256, 0, stream>>>(
      x_audio, midi, enc_w1, enc_b1, enc_w2, enc_b2, xs);

  const int XBS0  = T_ * C_ * HW;  // x_audio batch stride
  const int HBS32 = 32 * HW;
  dim3 blk(256);
  dim3 g128(16, 4, 16);

  // layer 0, both directions (bwd step s consumes time 7-s, writes seq0[7-s] ch 32:64)
  for (int s = 0; s < 8; ++s) {
    int t = s;
    conv_step<16, true, 128><<<g128, blk, 0, stream>>>(
        xs + (size_t)t * C_ * HW, XBS0,
        s ? seq0 + (size_t)(t - 1) * B64HW : nullptr, SBS,
        wt0f, b0f, s ? c0f : nullptr, c0f,
        seq0 + (size_t)t * B64HW, SBS, s ? 48 : 16);
    int tb = 7 - s;
    conv_step<16, true, 128><<<g128, blk, 0, stream>>>(
        xs + (size_t)tb * C_ * HW, XBS0,
        s ? seq0 + (size_t)(tb + 1) * B64HW + 32 * HW : nullptr, SBS,
        wt0b, b0b, s ? c0b : nullptr, c0b,
        seq0 + (size_t)tb * B64HW + 32 * HW, SBS, s ? 48 : 16);
  }

  // layer 1 forward (h ping-pong: h_out at step s = (s&1)?h1p1:h1p0)
  for (int s = 0; s < 8; ++s) {
    conv_step<64, true, 128><<<g128, blk, 0, stream>>>(
        seq0 + (size_t)s * B64HW, SBS,
        s ? ((s & 1) ? h1p0 : h1p1) : nullptr, HBS32,
        wt1f, b1f, s ? c1f : nullptr, c1f,
        (s & 1) ? h1p1 : h1p0, HBS32, s ? 96 : 64);
  }

  // layer 1 backward: only step 0 of the reversed scan is needed (h,c = 0, input t=7)
  conv_step<64, true, 128><<<g128, blk, 0, stream>>>(
      seq0 + (size_t)7 * B64HW, SBS,
      nullptr, 0, wt1b, b1b, nullptr, c1bw,
      h1bw, HBS32, 64);

  // final conv: concat(h1 fwd last = h1p1, h1 bwd = h1bw) -> out [B,64,64,64]
  dim3 g64(16, 2, 16);
  conv_step<32, false, 64><<<g64, blk, 0, stream>>>(
      h1p1, HBS32, h1bw, HBS32, wtfc, fcb,
      nullptr, nullptr, out, 64 * HW, 64);
}

// Round 2
// 547.453 us; speedup vs baseline: 7.0700x; 7.0700x over previous
//
#include <hip/hip_runtime.h>

typedef _Float16 f16;
typedef _Float16 f16x8 __attribute__((ext_vector_type(8)));
typedef float f32x16 __attribute__((ext_vector_type(16)));

namespace {

constexpr int B_ = 16, T_ = 8, HW = 4096;

__device__ __forceinline__ float sigm(float x)  { return 1.f / (1.f + __expf(-x)); }
__device__ __forceinline__ float ftanh(float x) { return 1.f - 2.f / (1.f + __expf(2.f * x)); }

__device__ __forceinline__ f32x16 zero16() {
  f32x16 v;
#pragma unroll
  for (int i = 0; i < 16; ++i) v[i] = 0.f;
  return v;
}

// ---------------- weight arrangement ----------------
// src OIHW f32 [NCO][CIN][3][3] -> dst f16 [dydx][kc][co][16]  (k16-contiguous per co)
struct WSet { const float* src; f16* dst; int KC, NCO, CIN; };

__global__ void warr_kernel(WSet s0, WSet s1, WSet s2, WSet s3, WSet s4) {
  WSet s = s0;
  switch (blockIdx.y) { case 1: s = s1; break; case 2: s = s2; break;
                        case 3: s = s3; break; case 4: s = s4; break; default: break; }
  int n = 9 * s.KC * s.NCO * 16;
  int i = blockIdx.x * 256 + threadIdx.x;
  if (i >= n) return;
  int kk = i & 15;
  int t = i >> 4;
  int co = t % s.NCO;
  int dkc = t / s.NCO;
  int kc = dkc % s.KC, dydx = dkc / s.KC;
  int ci = kc * 16 + kk;
  float v = (ci < s.CIN) ? s.src[(co * s.CIN + ci) * 9 + dydx] : 0.f;
  s.dst[i] = (f16)v;
}

// ---------------- positional encoding + add, NHWC f16 out ----------------
// xs layout: [B*T][4096][16] f16
__global__ void pe_kernel(const float* __restrict__ xa, const float* __restrict__ midi,
                          const float* __restrict__ w1, const float* __restrict__ b1,
                          const float* __restrict__ w2, const float* __restrict__ b2,
                          f16* __restrict__ xs) {
  int gid = blockIdx.x * 256 + threadIdx.x;   // one 16B unit (8 channels)
  int half = gid & 1;
  int gpx = gid >> 1;                         // (bt, pixel)
  int bt = gpx >> 12, gp = gpx & 4095;
  float n0 = -0.5f + midi[bt * 2 + 0] * (1.f / 64.f);
  float n1 = -0.5f + midi[bt * 2 + 1] * (1.f / 64.f);
  float hk[4];
#pragma unroll
  for (int k = 0; k < 4; ++k)
    hk[k] = fmaxf(fmaf(n0, w1[k], fmaf(n1, w1[4 + k], b1[k])), 0.f);
  f16x8 ov;
#pragma unroll
  for (int j = 0; j < 8; ++j) {
    int c = half * 8 + j;
    long p = (long)c * HW + gp;
    float z = b2[p];
#pragma unroll
    for (int k = 0; k < 4; ++k) z = fmaf(hk[k], w2[(long)k * 65536 + p], z);
    ov[j] = (f16)(xa[(long)bt * 65536 + p] + ftanh(z));
  }
  *reinterpret_cast<f16x8*>(xs + (long)gpx * 16 + half * 8) = ov;
}

// ---------------- MFMA conv / ConvLSTM step ----------------
// Tile: 128 pixels (8 rows x 16 cols), N = NCO. 4 waves = 2 m-groups x 2 n-groups.
// A (activations) from LDS NHWC tile [10][18][CINPAD]; B (weights) from global W'.
struct ConvDir {
  const f16* x;  long xbs;   // batch stride (elements)
  const f16* h;  long hbs;
  const f16* w;
  const float* bias;
  const float* cin;
  float* cout;               // c-state out, or final f32 output for !GATES
  f16* hout; long hobs;
  int kc;                    // runtime active k16-chunk count
};

template<int CIN1, int CIN2, int CINPAD, int KCF, int HST, int HOST, bool GATES, int NCO>
__global__ __launch_bounds__(256, 4)
void conv_mfma(ConvDir p0, ConvDir p1)
{
  constexpr int ACT_BYTES = 180 * CINPAD * 2;
  constexpr int ZB_BYTES  = GATES ? 64 * 128 * 4 : 0;
  constexpr int SMEM = ACT_BYTES > ZB_BYTES ? ACT_BYTES : ZB_BYTES;
  __shared__ __align__(16) char smem[SMEM];
  f16*   act  = (f16*)smem;
  float* zbuf = (float*)smem;

  const ConvDir P = blockIdx.y ? p1 : p0;
  const int b = blockIdx.z;
  const int tileY = blockIdx.x >> 2, tileX = blockIdx.x & 3;
  const int gy0 = tileY * 8, gx0 = tileX * 16;
  const int tid = threadIdx.x;

  // ---- stage activation tile: [10][18][CINPAD], units of 8 f16 ----
  constexpr int UPX = CIN1 / 8, UPH = CIN2 / 8, UPP = UPX + UPH;
  const bool have_h = (P.h != nullptr);
  for (int i = tid; i < 180 * UPP; i += 256) {
    int px = i / UPP, u = i - px * UPP;
    if (u >= UPX && !have_h) continue;
    int py = px / 18, pxx = px - py * 18;
    int gy = gy0 + py - 1, gx = gx0 + pxx - 1;
    f16x8 v;
#pragma unroll
    for (int j = 0; j < 8; ++j) v[j] = (f16)0.f;
    if ((unsigned)gy < 64u && (unsigned)gx < 64u) {
      long gp = (long)gy * 64 + gx;
      const f16* src = (u < UPX) ? (P.x + b * P.xbs + gp * CIN1 + u * 8)
                                 : (P.h + b * P.hbs + gp * HST + (u - UPX) * 8);
      v = *reinterpret_cast<const f16x8*>(src);
    }
    *reinterpret_cast<f16x8*>(act + px * CINPAD + u * 8) = v;
  }
  __syncthreads();

  const int lane = tid & 63, wv = tid >> 6;
  const int mg = wv & 1, ng = wv >> 1;
  constexpr int NF = NCO / 64;                 // n-frags per n-group: 128->2, 64->1
  const int rl = lane & 31;
  const int khalf = (lane >> 5) * 8;
  const int laneA = ((rl >> 4) * 18 + (rl & 15)) * CINPAD + khalf;   // f16 units
  const int laneB = rl * 16 + khalf;                                  // f16 units

  f32x16 acc[2][NF];
#pragma unroll
  for (int m = 0; m < 2; ++m)
#pragma unroll
    for (int nf = 0; nf < NF; ++nf) acc[m][nf] = zero16();

  const int KCn = P.kc;
  const f16* __restrict__ wbase = P.w;

#pragma unroll
  for (int dy = 0; dy < 3; ++dy)
#pragma unroll
  for (int dx = 0; dx < 3; ++dx) {
    const int dydx = dy * 3 + dx;
    const f16* arow = act + laneA + dx * CINPAD;
    for (int kc = 0; kc < KCn; ++kc) {
      f16x8 bf[NF];
#pragma unroll
      for (int nf = 0; nf < NF; ++nf)
        bf[nf] = *reinterpret_cast<const f16x8*>(
            wbase + ((long)(dydx * KCF + kc) * NCO + (ng * NF + nf) * 32) * 16 + laneB);
#pragma unroll
      for (int m = 0; m < 2; ++m) {
        const int mf = mg * 2 + m;
        f16x8 af = *reinterpret_cast<const f16x8*>(
            arow + ((mf * 2 + dy) * 18) * CINPAD + kc * 16);
#pragma unroll
        for (int nf = 0; nf < NF; ++nf)
          acc[m][nf] = __builtin_amdgcn_mfma_f32_32x32x16_f16(af, bf[nf], acc[m][nf], 0, 0, 0);
      }
    }
  }

  __syncthreads();

  if constexpr (GATES) {
    // two phases over m-groups; zbuf = [64 px][128 co] f32
#pragma unroll
    for (int phase = 0; phase < 2; ++phase) {
      if (mg == phase) {
#pragma unroll
        for (int m = 0; m < 2; ++m) {
#pragma unroll
          for (int nf = 0; nf < NF; ++nf) {
            const int col = (ng * NF + nf) * 32 + rl;
            const float bs = P.bias[col];
#pragma unroll
            for (int r = 0; r < 16; ++r) {
              int row = (r & 3) + 8 * (r >> 2) + 4 * (lane >> 5);
              zbuf[(m * 32 + row) * 128 + col] = acc[m][nf][r] + bs;
            }
          }
        }
      }
      __syncthreads();
      const int hid = tid & 31;
#pragma unroll
      for (int i = 0; i < 8; ++i) {
        int pl = (tid >> 5) + i * 8;             // 0..63
        int pxt = phase * 64 + pl;
        int py = pxt >> 4, pxx = pxt & 15;
        long gp = (long)(gy0 + py) * 64 + (gx0 + pxx);
        float zi = zbuf[pl * 128 + hid];
        float zf = zbuf[pl * 128 + 32 + hid];
        float zo = zbuf[pl * 128 + 64 + hid];
        float zg = zbuf[pl * 128 + 96 + hid];
        long cidx = ((long)b * HW + gp) * 32 + hid;
        float cp = P.cin ? P.cin[cidx] : 0.f;
        float c2 = sigm(zf) * cp + sigm(zi) * ftanh(zg);
        P.cout[cidx] = c2;
        P.hout[b * P.hobs + gp * HOST + hid] = (f16)(sigm(zo) * ftanh(c2));
      }
      __syncthreads();
    }
  } else {
    // final conv: direct f32 NCHW store (P.cout = output)
#pragma unroll
    for (int m = 0; m < 2; ++m) {
#pragma unroll
      for (int nf = 0; nf < NF; ++nf) {
        const int co = (ng * NF + nf) * 32 + rl;
        const float bs = P.bias[co];
#pragma unroll
        for (int r = 0; r < 16; ++r) {
          int row = (r & 3) + 8 * (r >> 2) + 4 * (lane >> 5);
          int pxt = (mg * 2 + m) * 32 + row;
          int py = pxt >> 4, pxx = pxt & 15;
          long gp = (long)(gy0 + py) * 64 + (gx0 + pxx);
          P.cout[((long)b * NCO + co) * HW + gp] = acc[m][nf][r] + bs;
        }
      }
    }
  }
}

} // namespace

extern "C" void kernel_launch(void* const* d_in, const int* in_sizes, int n_in,
                              void* d_out, int out_size, void* d_ws, size_t ws_size,
                              hipStream_t stream) {
  const float* x_audio = (const float*)d_in[0];
  const float* midi    = (const float*)d_in[1];
  const float* enc_w1  = (const float*)d_in[2];
  const float* enc_b1  = (const float*)d_in[3];
  const float* enc_w2  = (const float*)d_in[4];
  const float* enc_b2  = (const float*)d_in[5];
  const float* w0f = (const float*)d_in[6];
  const float* b0f = (const float*)d_in[7];
  const float* w0b = (const float*)d_in[8];
  const float* b0b = (const float*)d_in[9];
  const float* w1f = (const float*)d_in[10];
  const float* b1f = (const float*)d_in[11];
  const float* w1b = (const float*)d_in[12];
  const float* b1b = (const float*)d_in[13];
  const float* fcw = (const float*)d_in[14];
  const float* fcb = (const float*)d_in[15];

  char* ws = (char*)d_ws;
  size_t off = 0;
  auto alloc = [&](size_t bytes) { char* p = ws + off; off += (bytes + 255) & ~(size_t)255; return p; };

  f16* xs    = (f16*)alloc((size_t)B_ * T_ * HW * 16 * 2);   // [B*T][4096][16]
  f16* seq0  = (f16*)alloc((size_t)T_ * B_ * HW * 64 * 2);   // [T][B][4096][64]
  float* c0f = (float*)alloc((size_t)B_ * HW * 32 * 4);
  float* c0b = (float*)alloc((size_t)B_ * HW * 32 * 4);
  float* c1f = (float*)alloc((size_t)B_ * HW * 32 * 4);
  float* c1bw= (float*)alloc((size_t)B_ * HW * 32 * 4);
  f16* h1p0  = (f16*)alloc((size_t)B_ * HW * 32 * 2);
  f16* h1p1  = (f16*)alloc((size_t)B_ * HW * 32 * 2);
  f16* h1bw  = (f16*)alloc((size_t)B_ * HW * 32 * 2);
  f16* wt0f  = (f16*)alloc((size_t)9 * 3 * 128 * 16 * 2);
  f16* wt0b  = (f16*)alloc((size_t)9 * 3 * 128 * 16 * 2);
  f16* wt1f  = (f16*)alloc((size_t)9 * 6 * 128 * 16 * 2);
  f16* wt1b  = (f16*)alloc((size_t)9 * 6 * 128 * 16 * 2);
  f16* wtfc  = (f16*)alloc((size_t)9 * 4 * 64 * 16 * 2);

  // 1) arrange weights (5 sets, one launch)
  {
    WSet s0{w0f, wt0f, 3, 128, 48}, s1{w0b, wt0b, 3, 128, 48};
    WSet s2{w1f, wt1f, 6, 128, 96}, s3{w1b, wt1b, 6, 128, 96};
    WSet s4{fcw, wtfc, 4, 64, 64};
    warr_kernel<<<dim3(432, 5), 256, 0, stream>>>(s0, s1, s2, s3, s4);
  }

  // 2) positional encoding -> xs (NHWC f16)
  pe_kernel<<<(B_ * T_ * HW * 2) / 256, 256, 0, stream>>>(
      x_audio, midi, enc_w1, enc_b1, enc_w2, enc_b2, xs);

  const long XSB  = (long)T_ * HW * 16;   // xs batch stride
  const long SLAB = (long)B_ * HW * 64;   // seq0 time slab
  const long SB   = (long)HW * 64;        // seq0 batch stride
  const long HB   = (long)HW * 32;        // 32-ch batch stride

  // 3) layer 0, fwd + bwd merged per step
  for (int s = 0; s < 8; ++s) {
    int tf = s, tb = 7 - s;
    ConvDir f{xs + (long)tf * HW * 16, XSB,
              s ? seq0 + (long)(tf - 1) * SLAB : nullptr, SB,
              wt0f, b0f, s ? c0f : nullptr, c0f,
              seq0 + (long)tf * SLAB, SB, s ? 3 : 1};
    ConvDir r{xs + (long)tb * HW * 16, XSB,
              s ? seq0 + (long)(tb + 1) * SLAB + 32 : nullptr, SB,
              wt0b, b0b, s ? c0b : nullptr, c0b,
              seq0 + (long)tb * SLAB + 32, SB, s ? 3 : 1};
    conv_mfma<16, 32, 56, 3, 64, 64, true, 128>
        <<<dim3(32, 2, 16), 256, 0, stream>>>(f, r);
  }

  // 4) layer 1: step 0 fwd merged with the single needed bwd step (t=7, zero state)
  {
    ConvDir f{seq0, SB, nullptr, HB, wt1f, b1f, nullptr, c1f, h1p0, HB, 4};
    ConvDir r{seq0 + 7 * SLAB, SB, nullptr, HB, wt1b, b1b, nullptr, c1bw, h1bw, HB, 4};
    conv_mfma<64, 32, 104, 6, 32, 32, true, 128>
        <<<dim3(32, 2, 16), 256, 0, stream>>>(f, r);
  }
  for (int s = 1; s < 8; ++s) {
    f16* hprev = (s & 1) ? h1p0 : h1p1;
    f16* hcur  = (s & 1) ? h1p1 : h1p0;
    ConvDir f{seq0 + (long)s * SLAB, SB, hprev, HB, wt1f, b1f, c1f, c1f, hcur, HB, 6};
    conv_mfma<64, 32, 104, 6, 32, 32, true, 128>
        <<<dim3(32, 1, 16), 256, 0, stream>>>(f, f);
  }

  // 5) final conv: concat(h1p1, h1bw) -> d_out f32 NCHW [B][64][64][64]
  {
    ConvDir f{h1p1, HB, h1bw, HB, wtfc, fcb, nullptr, (float*)d_out, nullptr, 0, 4};
    conv_mfma<32, 32, 72, 4, 32, 32, false, 64>
        <<<dim3(32, 1, 16), 256, 0, stream>>>(f, f);
  }
}

// Round 3
// 540.682 us; speedup vs baseline: 7.1585x; 1.0125x over previous
//
#include <hip/hip_runtime.h>

typedef _Float16 f16;
typedef _Float16 f16x8 __attribute__((ext_vector_type(8)));
typedef float f32x16 __attribute__((ext_vector_type(16)));

namespace {

constexpr int B_ = 16, T_ = 8, HW = 4096;

__device__ __forceinline__ float sigm(float x)  { return 1.f / (1.f + __expf(-x)); }
__device__ __forceinline__ float ftanh(float x) { return 1.f - 2.f / (1.f + __expf(2.f * x)); }

__device__ __forceinline__ f32x16 zero16() {
  f32x16 v;
#pragma unroll
  for (int i = 0; i < 16; ++i) v[i] = 0.f;
  return v;
}

// ---------------- weight arrangement ----------------
// src OIHW f32 [NCO][CIN][3][3] -> dst f16 [dydx][kc][co][16]  (k16-contiguous per co)
struct WSet { const float* src; f16* dst; int KC, NCO, CIN; };

__global__ void warr_kernel(WSet s0, WSet s1, WSet s2, WSet s3, WSet s4) {
  WSet s = s0;
  switch (blockIdx.y) { case 1: s = s1; break; case 2: s = s2; break;
                        case 3: s = s3; break; case 4: s = s4; break; default: break; }
  int n = 9 * s.KC * s.NCO * 16;
  int i = blockIdx.x * 256 + threadIdx.x;
  if (i >= n) return;
  int kk = i & 15;
  int t = i >> 4;
  int co = t % s.NCO;
  int dkc = t / s.NCO;
  int kc = dkc % s.KC, dydx = dkc / s.KC;
  int ci = kc * 16 + kk;
  float v = (ci < s.CIN) ? s.src[(co * s.CIN + ci) * 9 + dydx] : 0.f;
  s.dst[i] = (f16)v;
}

// ---------------- positional encoding + add, NHWC f16 out ----------------
// xs layout: [B*T][4096][16] f16
__global__ void pe_kernel(const float* __restrict__ xa, const float* __restrict__ midi,
                          const float* __restrict__ w1, const float* __restrict__ b1,
                          const float* __restrict__ w2, const float* __restrict__ b2,
                          f16* __restrict__ xs) {
  int gid = blockIdx.x * 256 + threadIdx.x;   // one 16B unit (8 channels)
  int half = gid & 1;
  int gpx = gid >> 1;                         // (bt, pixel)
  int bt = gpx >> 12, gp = gpx & 4095;
  float n0 = -0.5f + midi[bt * 2 + 0] * (1.f / 64.f);
  float n1 = -0.5f + midi[bt * 2 + 1] * (1.f / 64.f);
  float hk[4];
#pragma unroll
  for (int k = 0; k < 4; ++k)
    hk[k] = fmaxf(fmaf(n0, w1[k], fmaf(n1, w1[4 + k], b1[k])), 0.f);
  f16x8 ov;
#pragma unroll
  for (int j = 0; j < 8; ++j) {
    int c = half * 8 + j;
    long p = (long)c * HW + gp;
    float z = b2[p];
#pragma unroll
    for (int k = 0; k < 4; ++k) z = fmaf(hk[k], w2[(long)k * 65536 + p], z);
    ov[j] = (f16)(xa[(long)bt * 65536 + p] + ftanh(z));
  }
  *reinterpret_cast<f16x8*>(xs + (long)gpx * 16 + half * 8) = ov;
}

// ---------------- MFMA conv / ConvLSTM step ----------------
// Tile: 128 pixels (8 rows x 16 cols), N = NCO. 4 waves = 2 m-groups x 2 n-groups.
// A (activations) from LDS NHWC tile [10][18][CINPAD]; B (weights) from global W'.
// K-loop fully unrolled (KC compile-time), barrier-free -> compiler pipelines loads.
struct ConvDir {
  const f16* x;  long xbs;   // batch stride (elements)
  const f16* h;  long hbs;
  const f16* w;
  const float* bias;
  const float* cin;
  float* cout;               // c-state out, or final f32 output for !GATES
  f16* hout; long hobs;
};

template<int CIN1, int CIN2, int CINPAD, int KCF, int KC, int HST, int HOST, bool GATES, int NCO>
__global__ __launch_bounds__(256, 2)
void conv_mfma(ConvDir p0, ConvDir p1)
{
  constexpr int ACT_BYTES = 180 * CINPAD * 2;
  constexpr int ZB_BYTES  = GATES ? 64 * 128 * 4 : 0;
  constexpr int SMEM = ACT_BYTES > ZB_BYTES ? ACT_BYTES : ZB_BYTES;
  __shared__ __align__(16) char smem[SMEM];
  f16*   act  = (f16*)smem;
  float* zbuf = (float*)smem;

  const ConvDir P = blockIdx.y ? p1 : p0;
  const int b = blockIdx.z;
  const int tileY = blockIdx.x >> 2, tileX = blockIdx.x & 3;
  const int gy0 = tileY * 8, gx0 = tileX * 16;
  const int tid = threadIdx.x;

  // ---- stage activation tile: [10][18][CINPAD], units of 8 f16 ----
  constexpr int UPX = CIN1 / 8, UPH = CIN2 / 8, UPP = UPX + UPH;
  const bool have_h = (P.h != nullptr);
  for (int i = tid; i < 180 * UPP; i += 256) {
    int px = i / UPP, u = i - px * UPP;
    if (u >= UPX && !have_h) continue;
    int py = px / 18, pxx = px - py * 18;
    int gy = gy0 + py - 1, gx = gx0 + pxx - 1;
    f16x8 v;
#pragma unroll
    for (int j = 0; j < 8; ++j) v[j] = (f16)0.f;
    if ((unsigned)gy < 64u && (unsigned)gx < 64u) {
      long gp = (long)gy * 64 + gx;
      const f16* src = (u < UPX) ? (P.x + b * P.xbs + gp * CIN1 + u * 8)
                                 : (P.h + b * P.hbs + gp * HST + (u - UPX) * 8);
      v = *reinterpret_cast<const f16x8*>(src);
    }
    *reinterpret_cast<f16x8*>(act + px * CINPAD + u * 8) = v;
  }
  __syncthreads();

  const int lane = tid & 63, wv = tid >> 6;
  const int mg = wv & 1, ng = wv >> 1;
  constexpr int NF = NCO / 64;                 // n-frags per n-group: 128->2, 64->1
  const int rl = lane & 31;
  const int khalf = (lane >> 5) * 8;
  const int laneA = ((rl >> 4) * 18 + (rl & 15)) * CINPAD + khalf;   // f16 units
  const int laneB = rl * 16 + khalf;                                  // f16 units

  f32x16 acc[2][NF];
#pragma unroll
  for (int m = 0; m < 2; ++m)
#pragma unroll
    for (int nf = 0; nf < NF; ++nf) acc[m][nf] = zero16();

  const f16* __restrict__ wng = P.w + laneB;
  const f16* __restrict__ arow = act + laneA;

#pragma unroll
  for (int dy = 0; dy < 3; ++dy)
#pragma unroll
  for (int dx = 0; dx < 3; ++dx) {
    const int dydx = dy * 3 + dx;
    f16x8 bf[KC][NF];
#pragma unroll
    for (int kc = 0; kc < KC; ++kc)
#pragma unroll
      for (int nf = 0; nf < NF; ++nf)
        bf[kc][nf] = *reinterpret_cast<const f16x8*>(
            wng + ((long)(dydx * KCF + kc) * NCO + (ng * NF + nf) * 32) * 16);
    f16x8 af[2][KC];
#pragma unroll
    for (int m = 0; m < 2; ++m)
#pragma unroll
      for (int kc = 0; kc < KC; ++kc)
        af[m][kc] = *reinterpret_cast<const f16x8*>(
            arow + dx * CINPAD + (((mg * 2 + m) * 2 + dy) * 18) * CINPAD + kc * 16);
#pragma unroll
    for (int kc = 0; kc < KC; ++kc)
#pragma unroll
      for (int m = 0; m < 2; ++m)
#pragma unroll
        for (int nf = 0; nf < NF; ++nf)
          acc[m][nf] = __builtin_amdgcn_mfma_f32_32x32x16_f16(af[m][kc], bf[kc][nf], acc[m][nf], 0, 0, 0);
  }

  __syncthreads();

  if constexpr (GATES) {
    // two phases over m-groups; zbuf = [64 px][128 co] f32
#pragma unroll
    for (int phase = 0; phase < 2; ++phase) {
      if (mg == phase) {
#pragma unroll
        for (int m = 0; m < 2; ++m) {
#pragma unroll
          for (int nf = 0; nf < NF; ++nf) {
            const int col = (ng * NF + nf) * 32 + rl;
            const float bs = P.bias[col];
#pragma unroll
            for (int r = 0; r < 16; ++r) {
              int row = (r & 3) + 8 * (r >> 2) + 4 * (lane >> 5);
              zbuf[(m * 32 + row) * 128 + col] = acc[m][nf][r] + bs;
            }
          }
        }
      }
      __syncthreads();
      const int hid = tid & 31;
#pragma unroll
      for (int i = 0; i < 8; ++i) {
        int pl = (tid >> 5) + i * 8;             // 0..63
        int pxt = phase * 64 + pl;
        int py = pxt >> 4, pxx = pxt & 15;
        long gp = (long)(gy0 + py) * 64 + (gx0 + pxx);
        float zi = zbuf[pl * 128 + hid];
        float zf = zbuf[pl * 128 + 32 + hid];
        float zo = zbuf[pl * 128 + 64 + hid];
        float zg = zbuf[pl * 128 + 96 + hid];
        long cidx = ((long)b * HW + gp) * 32 + hid;
        float cp = P.cin ? P.cin[cidx] : 0.f;
        float c2 = sigm(zf) * cp + sigm(zi) * ftanh(zg);
        P.cout[cidx] = c2;
        P.hout[b * P.hobs + gp * HOST + hid] = (f16)(sigm(zo) * ftanh(c2));
      }
      __syncthreads();
    }
  } else {
    // final conv: direct f32 NCHW store (P.cout = output)
#pragma unroll
    for (int m = 0; m < 2; ++m) {
#pragma unroll
      for (int nf = 0; nf < NF; ++nf) {
        const int co = (ng * NF + nf) * 32 + rl;
        const float bs = P.bias[co];
#pragma unroll
        for (int r = 0; r < 16; ++r) {
          int row = (r & 3) + 8 * (r >> 2) + 4 * (lane >> 5);
          int pxt = (mg * 2 + m) * 32 + row;
          int py = pxt >> 4, pxx = pxt & 15;
          long gp = (long)(gy0 + py) * 64 + (gx0 + pxx);
          P.cout[((long)b * NCO + co) * HW + gp] = acc[m][nf][r] + bs;
        }
      }
    }
  }
}

} // namespace

extern "C" void kernel_launch(void* const* d_in, const int* in_sizes, int n_in,
                              void* d_out, int out_size, void* d_ws, size_t ws_size,
                              hipStream_t stream) {
  const float* x_audio = (const float*)d_in[0];
  const float* midi    = (const float*)d_in[1];
  const float* enc_w1  = (const float*)d_in[2];
  const float* enc_b1  = (const float*)d_in[3];
  const float* enc_w2  = (const float*)d_in[4];
  const float* enc_b2  = (const float*)d_in[5];
  const float* w0f = (const float*)d_in[6];
  const float* b0f = (const float*)d_in[7];
  const float* w0b = (const float*)d_in[8];
  const float* b0b = (const float*)d_in[9];
  const float* w1f = (const float*)d_in[10];
  const float* b1f = (const float*)d_in[11];
  const float* w1b = (const float*)d_in[12];
  const float* b1b = (const float*)d_in[13];
  const float* fcw = (const float*)d_in[14];
  const float* fcb = (const float*)d_in[15];

  char* ws = (char*)d_ws;
  size_t off = 0;
  auto alloc = [&](size_t bytes) { char* p = ws + off; off += (bytes + 255) & ~(size_t)255; return p; };

  f16* xs    = (f16*)alloc((size_t)B_ * T_ * HW * 16 * 2);   // [B*T][4096][16]
  f16* seq0  = (f16*)alloc((size_t)T_ * B_ * HW * 64 * 2);   // [T][B][4096][64]
  float* c0f = (float*)alloc((size_t)B_ * HW * 32 * 4);
  float* c0b = (float*)alloc((size_t)B_ * HW * 32 * 4);
  float* c1f = (float*)alloc((size_t)B_ * HW * 32 * 4);
  float* c1bw= (float*)alloc((size_t)B_ * HW * 32 * 4);
  f16* h1p0  = (f16*)alloc((size_t)B_ * HW * 32 * 2);
  f16* h1p1  = (f16*)alloc((size_t)B_ * HW * 32 * 2);
  f16* h1bw  = (f16*)alloc((size_t)B_ * HW * 32 * 2);
  f16* wt0f  = (f16*)alloc((size_t)9 * 3 * 128 * 16 * 2);
  f16* wt0b  = (f16*)alloc((size_t)9 * 3 * 128 * 16 * 2);
  f16* wt1f  = (f16*)alloc((size_t)9 * 6 * 128 * 16 * 2);
  f16* wt1b  = (f16*)alloc((size_t)9 * 6 * 128 * 16 * 2);
  f16* wtfc  = (f16*)alloc((size_t)9 * 4 * 64 * 16 * 2);

  // 1) arrange weights (5 sets, one launch)
  {
    WSet s0{w0f, wt0f, 3, 128, 48}, s1{w0b, wt0b, 3, 128, 48};
    WSet s2{w1f, wt1f, 6, 128, 96}, s3{w1b, wt1b, 6, 128, 96};
    WSet s4{fcw, wtfc, 4, 64, 64};
    warr_kernel<<<dim3(432, 5), 256, 0, stream>>>(s0, s1, s2, s3, s4);
  }

  // 2) positional encoding -> xs (NHWC f16)
  pe_kernel<<<(B_ * T_ * HW * 2) / 256, 256, 0, stream>>>(
      x_audio, midi, enc_w1, enc_b1, enc_w2, enc_b2, xs);

  const long XSB  = (long)T_ * HW * 16;   // xs batch stride
  const long SLAB = (long)B_ * HW * 64;   // seq0 time slab
  const long SB   = (long)HW * 64;        // seq0 batch stride
  const long HB   = (long)HW * 32;        // 32-ch batch stride

  // 3) layer 0, fwd + bwd merged per step
  {
    // step 0: no h, K = 16 ch (KC=1)
    ConvDir f{xs, XSB, nullptr, SB, wt0f, b0f, nullptr, c0f, seq0, SB};
    ConvDir r{xs + (long)7 * HW * 16, XSB, nullptr, SB, wt0b, b0b, nullptr, c0b,
              seq0 + (long)7 * SLAB + 32, SB};
    conv_mfma<16, 32, 56, 3, 1, 64, 64, true, 128>
        <<<dim3(32, 2, 16), 256, 0, stream>>>(f, r);
  }
  for (int s = 1; s < 8; ++s) {
    int tf = s, tb = 7 - s;
    ConvDir f{xs + (long)tf * HW * 16, XSB,
              seq0 + (long)(tf - 1) * SLAB, SB,
              wt0f, b0f, c0f, c0f,
              seq0 + (long)tf * SLAB, SB};
    ConvDir r{xs + (long)tb * HW * 16, XSB,
              seq0 + (long)(tb + 1) * SLAB + 32, SB,
              wt0b, b0b, c0b, c0b,
              seq0 + (long)tb * SLAB + 32, SB};
    conv_mfma<16, 32, 56, 3, 3, 64, 64, true, 128>
        <<<dim3(32, 2, 16), 256, 0, stream>>>(f, r);
  }

  // 4) layer 1: step 0 fwd merged with the single needed bwd step (t=7, zero state)
  {
    ConvDir f{seq0, SB, nullptr, HB, wt1f, b1f, nullptr, c1f, h1p0, HB};
    ConvDir r{seq0 + 7 * SLAB, SB, nullptr, HB, wt1b, b1b, nullptr, c1bw, h1bw, HB};
    conv_mfma<64, 32, 104, 6, 4, 32, 32, true, 128>
        <<<dim3(32, 2, 16), 256, 0, stream>>>(f, r);
  }
  for (int s = 1; s < 8; ++s) {
    f16* hprev = (s & 1) ? h1p0 : h1p1;
    f16* hcur  = (s & 1) ? h1p1 : h1p0;
    ConvDir f{seq0 + (long)s * SLAB, SB, hprev, HB, wt1f, b1f, c1f, c1f, hcur, HB};
    conv_mfma<64, 32, 104, 6, 6, 32, 32, true, 128>
        <<<dim3(32, 1, 16), 256, 0, stream>>>(f, f);
  }

  // 5) final conv: concat(h1p1, h1bw) -> d_out f32 NCHW [B][64][64][64]
  {
    ConvDir f{h1p1, HB, h1bw, HB, wtfc, fcb, nullptr, (float*)d_out, nullptr, 0};
    conv_mfma<32, 32, 72, 4, 4, 32, 32, false, 64>
        <<<dim3(32, 1, 16), 256, 0, stream>>>(f, f);
  }
}

// Round 4
// 516.672 us; speedup vs baseline: 7.4912x; 1.0465x over previous
//
#include <hip/hip_runtime.h>

typedef _Float16 f16;
typedef _Float16 f16x8 __attribute__((ext_vector_type(8)));
typedef float f32x16 __attribute__((ext_vector_type(16)));

namespace {

constexpr int B_ = 16, T_ = 8, HW = 4096;

__device__ __forceinline__ float sigm(float x)  { return 1.f / (1.f + __expf(-x)); }
__device__ __forceinline__ float ftanh(float x) { return 1.f - 2.f / (1.f + __expf(2.f * x)); }

__device__ __forceinline__ f32x16 zero16() {
  f32x16 v;
#pragma unroll
  for (int i = 0; i < 16; ++i) v[i] = 0.f;
  return v;
}

// ---------------- weight arrangement ----------------
// src OIHW f32 [NCO][CIN][3][3] -> dst f16 [dydx][kc][co][16]  (k16-contiguous per co)
struct WSet { const float* src; f16* dst; int KC, NCO, CIN; };

__global__ void warr_kernel(WSet s0, WSet s1, WSet s2, WSet s3, WSet s4) {
  WSet s = s0;
  switch (blockIdx.y) { case 1: s = s1; break; case 2: s = s2; break;
                        case 3: s = s3; break; case 4: s = s4; break; default: break; }
  int n = 9 * s.KC * s.NCO * 16;
  int i = blockIdx.x * 256 + threadIdx.x;
  if (i >= n) return;
  int kk = i & 15;
  int t = i >> 4;
  int co = t % s.NCO;
  int dkc = t / s.NCO;
  int kc = dkc % s.KC, dydx = dkc / s.KC;
  int ci = kc * 16 + kk;
  float v = (ci < s.CIN) ? s.src[(co * s.CIN + ci) * 9 + dydx] : 0.f;
  s.dst[i] = (f16)v;
}

// ---------------- positional encoding + add, NHWC f16 out ----------------
// xs layout: [B*T][4096][16] f16
__global__ void pe_kernel(const float* __restrict__ xa, const float* __restrict__ midi,
                          const float* __restrict__ w1, const float* __restrict__ b1,
                          const float* __restrict__ w2, const float* __restrict__ b2,
                          f16* __restrict__ xs) {
  int gid = blockIdx.x * 256 + threadIdx.x;   // one 16B unit (8 channels)
  int half = gid & 1;
  int gpx = gid >> 1;                         // (bt, pixel)
  int bt = gpx >> 12, gp = gpx & 4095;
  float n0 = -0.5f + midi[bt * 2 + 0] * (1.f / 64.f);
  float n1 = -0.5f + midi[bt * 2 + 1] * (1.f / 64.f);
  float hk[4];
#pragma unroll
  for (int k = 0; k < 4; ++k)
    hk[k] = fmaxf(fmaf(n0, w1[k], fmaf(n1, w1[4 + k], b1[k])), 0.f);
  f16x8 ov;
#pragma unroll
  for (int j = 0; j < 8; ++j) {
    int c = half * 8 + j;
    long p = (long)c * HW + gp;
    float z = b2[p];
#pragma unroll
    for (int k = 0; k < 4; ++k) z = fmaf(hk[k], w2[(long)k * 65536 + p], z);
    ov[j] = (f16)(xa[(long)bt * 65536 + p] + ftanh(z));
  }
  *reinterpret_cast<f16x8*>(xs + (long)gpx * 16 + half * 8) = ov;
}

// ---------------- MFMA conv / ConvLSTM step ----------------
// Tile: 128 pixels (8 rows x 16 cols), N = NCO. 8 waves = MG m-groups x NG n-groups.
// A (activations) from LDS NHWC tile [10][18][CINPAD]; B (weights) from global W'.
// K-loop fully unrolled (KC compile-time), barrier-free.
struct ConvDir {
  const f16* x;  long xbs;   // batch stride (elements)
  const f16* h;  long hbs;
  const f16* w;
  const float* bias;
  const float* cin;
  float* cout;               // c-state out, or final f32 output for !GATES
  f16* hout; long hobs;
};

template<int CIN1, int CIN2, int CINPAD, int KCF, int KC, int HST, int HOST,
         bool GATES, int NCO, int MG, int MFRAG>
__global__ __launch_bounds__(512, 4)
void conv_mfma(ConvDir p0, ConvDir p1)
{
  constexpr int NG = 8 / MG;               // n-groups
  constexpr int NF = NCO / (NG * 32);      // n-frags per wave (1 here)
  constexpr int ACT_BYTES = 180 * CINPAD * 2;
  constexpr int ZB_BYTES  = GATES ? 64 * 128 * 4 : 0;
  constexpr int SMEM = ACT_BYTES > ZB_BYTES ? ACT_BYTES : ZB_BYTES;
  __shared__ __align__(16) char smem[SMEM];
  f16*   act  = (f16*)smem;
  float* zbuf = (float*)smem;

  const ConvDir P = blockIdx.y ? p1 : p0;
  const int b = blockIdx.z;
  const int tileY = blockIdx.x >> 2, tileX = blockIdx.x & 3;
  const int gy0 = tileY * 8, gx0 = tileX * 16;
  const int tid = threadIdx.x;

  // ---- stage activation tile: [10][18][CINPAD], units of 8 f16 ----
  constexpr int UPX = CIN1 / 8, UPH = CIN2 / 8, UPP = UPX + UPH;
  const bool have_h = (P.h != nullptr);
  for (int i = tid; i < 180 * UPP; i += 512) {
    int px = i / UPP, u = i - px * UPP;
    if (u >= UPX && !have_h) continue;
    int py = px / 18, pxx = px - py * 18;
    int gy = gy0 + py - 1, gx = gx0 + pxx - 1;
    f16x8 v;
#pragma unroll
    for (int j = 0; j < 8; ++j) v[j] = (f16)0.f;
    if ((unsigned)gy < 64u && (unsigned)gx < 64u) {
      long gp = (long)gy * 64 + gx;
      const f16* src = (u < UPX) ? (P.x + b * P.xbs + gp * CIN1 + u * 8)
                                 : (P.h + b * P.hbs + gp * HST + (u - UPX) * 8);
      v = *reinterpret_cast<const f16x8*>(src);
    }
    *reinterpret_cast<f16x8*>(act + px * CINPAD + u * 8) = v;
  }
  __syncthreads();

  const int lane = tid & 63, wv = tid >> 6;   // wv in [0,8)
  const int mg = wv % MG, ng = wv / MG;
  const int rl = lane & 31;
  const int khalf = (lane >> 5) * 8;
  const int laneA = ((rl >> 4) * 18 + (rl & 15)) * CINPAD + khalf;   // f16 units
  const int laneB = rl * 16 + khalf;                                  // f16 units

  f32x16 acc[MFRAG][NF];
#pragma unroll
  for (int m = 0; m < MFRAG; ++m)
#pragma unroll
    for (int nf = 0; nf < NF; ++nf) acc[m][nf] = zero16();

  const f16* __restrict__ wng = P.w + laneB;
  const f16* __restrict__ arow = act + laneA;

#pragma unroll
  for (int dy = 0; dy < 3; ++dy)
#pragma unroll
  for (int dx = 0; dx < 3; ++dx) {
    const int dydx = dy * 3 + dx;
    f16x8 bf[KC][NF];
#pragma unroll
    for (int kc = 0; kc < KC; ++kc)
#pragma unroll
      for (int nf = 0; nf < NF; ++nf)
        bf[kc][nf] = *reinterpret_cast<const f16x8*>(
            wng + ((long)(dydx * KCF + kc) * NCO + (ng * NF + nf) * 32) * 16);
    f16x8 af[MFRAG][KC];
#pragma unroll
    for (int m = 0; m < MFRAG; ++m)
#pragma unroll
      for (int kc = 0; kc < KC; ++kc)
        af[m][kc] = *reinterpret_cast<const f16x8*>(
            arow + dx * CINPAD + (((mg * MFRAG + m) * 2 + dy) * 18) * CINPAD + kc * 16);
#pragma unroll
    for (int kc = 0; kc < KC; ++kc)
#pragma unroll
      for (int m = 0; m < MFRAG; ++m)
#pragma unroll
        for (int nf = 0; nf < NF; ++nf)
          acc[m][nf] = __builtin_amdgcn_mfma_f32_32x32x16_f16(af[m][kc], bf[kc][nf], acc[m][nf], 0, 0, 0);
  }

  __syncthreads();

  if constexpr (GATES) {
    // two phases over m-groups (MG==2); zbuf = [64 px][128 co] f32
#pragma unroll
    for (int phase = 0; phase < 2; ++phase) {
      if (mg == phase) {
#pragma unroll
        for (int m = 0; m < MFRAG; ++m) {
#pragma unroll
          for (int nf = 0; nf < NF; ++nf) {
            const int col = (ng * NF + nf) * 32 + rl;
            const float bs = P.bias[col];
#pragma unroll
            for (int r = 0; r < 16; ++r) {
              int row = (r & 3) + 8 * (r >> 2) + 4 * (lane >> 5);
              zbuf[(m * 32 + row) * 128 + col] = acc[m][nf][r] + bs;
            }
          }
        }
      }
      __syncthreads();
      const int hid = tid & 31;
#pragma unroll
      for (int i = 0; i < 4; ++i) {
        int pl = (tid >> 5) + i * 16;            // 0..63
        int pxt = phase * 64 + pl;
        int py = pxt >> 4, pxx = pxt & 15;
        long gp = (long)(gy0 + py) * 64 + (gx0 + pxx);
        float zi = zbuf[pl * 128 + hid];
        float zf = zbuf[pl * 128 + 32 + hid];
        float zo = zbuf[pl * 128 + 64 + hid];
        float zg = zbuf[pl * 128 + 96 + hid];
        long cidx = ((long)b * HW + gp) * 32 + hid;
        float cp = P.cin ? P.cin[cidx] : 0.f;
        float c2 = sigm(zf) * cp + sigm(zi) * ftanh(zg);
        P.cout[cidx] = c2;
        P.hout[b * P.hobs + gp * HOST + hid] = (f16)(sigm(zo) * ftanh(c2));
      }
      __syncthreads();
    }
  } else {
    // final conv: direct f32 NCHW store (P.cout = output)
#pragma unroll
    for (int m = 0; m < MFRAG; ++m) {
#pragma unroll
      for (int nf = 0; nf < NF; ++nf) {
        const int co = (ng * NF + nf) * 32 + rl;
        const float bs = P.bias[co];
#pragma unroll
        for (int r = 0; r < 16; ++r) {
          int row = (r & 3) + 8 * (r >> 2) + 4 * (lane >> 5);
          int pxt = (mg * MFRAG + m) * 32 + row;
          int py = pxt >> 4, pxx = pxt & 15;
          long gp = (long)(gy0 + py) * 64 + (gx0 + pxx);
          P.cout[((long)b * NCO + co) * HW + gp] = acc[m][nf][r] + bs;
        }
      }
    }
  }
}

} // namespace

extern "C" void kernel_launch(void* const* d_in, const int* in_sizes, int n_in,
                              void* d_out, int out_size, void* d_ws, size_t ws_size,
                              hipStream_t stream) {
  const float* x_audio = (const float*)d_in[0];
  const float* midi    = (const float*)d_in[1];
  const float* enc_w1  = (const float*)d_in[2];
  const float* enc_b1  = (const float*)d_in[3];
  const float* enc_w2  = (const float*)d_in[4];
  const float* enc_b2  = (const float*)d_in[5];
  const float* w0f = (const float*)d_in[6];
  const float* b0f = (const float*)d_in[7];
  const float* w0b = (const float*)d_in[8];
  const float* b0b = (const float*)d_in[9];
  const float* w1f = (const float*)d_in[10];
  const float* b1f = (const float*)d_in[11];
  const float* w1b = (const float*)d_in[12];
  const float* b1b = (const float*)d_in[13];
  const float* fcw = (const float*)d_in[14];
  const float* fcb = (const float*)d_in[15];

  char* ws = (char*)d_ws;
  size_t off = 0;
  auto alloc = [&](size_t bytes) { char* p = ws + off; off += (bytes + 255) & ~(size_t)255; return p; };

  f16* xs    = (f16*)alloc((size_t)B_ * T_ * HW * 16 * 2);   // [B*T][4096][16]
  f16* seq0  = (f16*)alloc((size_t)T_ * B_ * HW * 64 * 2);   // [T][B][4096][64]
  float* c0f = (float*)alloc((size_t)B_ * HW * 32 * 4);
  float* c0b = (float*)alloc((size_t)B_ * HW * 32 * 4);
  float* c1f = (float*)alloc((size_t)B_ * HW * 32 * 4);
  float* c1bw= (float*)alloc((size_t)B_ * HW * 32 * 4);
  f16* h1p0  = (f16*)alloc((size_t)B_ * HW * 32 * 2);
  f16* h1p1  = (f16*)alloc((size_t)B_ * HW * 32 * 2);
  f16* h1bw  = (f16*)alloc((size_t)B_ * HW * 32 * 2);
  f16* wt0f  = (f16*)alloc((size_t)9 * 3 * 128 * 16 * 2);
  f16* wt0b  = (f16*)alloc((size_t)9 * 3 * 128 * 16 * 2);
  f16* wt1f  = (f16*)alloc((size_t)9 * 6 * 128 * 16 * 2);
  f16* wt1b  = (f16*)alloc((size_t)9 * 6 * 128 * 16 * 2);
  f16* wtfc  = (f16*)alloc((size_t)9 * 4 * 64 * 16 * 2);

  // 1) arrange weights (5 sets, one launch)
  {
    WSet s0{w0f, wt0f, 3, 128, 48}, s1{w0b, wt0b, 3, 128, 48};
    WSet s2{w1f, wt1f, 6, 128, 96}, s3{w1b, wt1b, 6, 128, 96};
    WSet s4{fcw, wtfc, 4, 64, 64};
    warr_kernel<<<dim3(432, 5), 256, 0, stream>>>(s0, s1, s2, s3, s4);
  }

  // 2) positional encoding -> xs (NHWC f16)
  pe_kernel<<<(B_ * T_ * HW * 2) / 256, 256, 0, stream>>>(
      x_audio, midi, enc_w1, enc_b1, enc_w2, enc_b2, xs);

  const long XSB  = (long)T_ * HW * 16;   // xs batch stride
  const long SLAB = (long)B_ * HW * 64;   // seq0 time slab
  const long SB   = (long)HW * 64;        // seq0 batch stride
  const long HB   = (long)HW * 32;        // 32-ch batch stride

  // 3) layer 0, fwd + bwd merged per step
  {
    // step 0: no h, K = 16 ch (KC=1)
    ConvDir f{xs, XSB, nullptr, SB, wt0f, b0f, nullptr, c0f, seq0, SB};
    ConvDir r{xs + (long)7 * HW * 16, XSB, nullptr, SB, wt0b, b0b, nullptr, c0b,
              seq0 + (long)7 * SLAB + 32, SB};
    conv_mfma<16, 32, 56, 3, 1, 64, 64, true, 128, 2, 2>
        <<<dim3(32, 2, 16), 512, 0, stream>>>(f, r);
  }
  for (int s = 1; s < 8; ++s) {
    int tf = s, tb = 7 - s;
    ConvDir f{xs + (long)tf * HW * 16, XSB,
              seq0 + (long)(tf - 1) * SLAB, SB,
              wt0f, b0f, c0f, c0f,
              seq0 + (long)tf * SLAB, SB};
    ConvDir r{xs + (long)tb * HW * 16, XSB,
              seq0 + (long)(tb + 1) * SLAB + 32, SB,
              wt0b, b0b, c0b, c0b,
              seq0 + (long)tb * SLAB + 32, SB};
    conv_mfma<16, 32, 56, 3, 3, 64, 64, true, 128, 2, 2>
        <<<dim3(32, 2, 16), 512, 0, stream>>>(f, r);
  }

  // 4) layer 1: step 0 fwd merged with the single needed bwd step (t=7, zero state)
  {
    ConvDir f{seq0, SB, nullptr, HB, wt1f, b1f, nullptr, c1f, h1p0, HB};
    ConvDir r{seq0 + 7 * SLAB, SB, nullptr, HB, wt1b, b1b, nullptr, c1bw, h1bw, HB};
    conv_mfma<64, 32, 104, 6, 4, 32, 32, true, 128, 2, 2>
        <<<dim3(32, 2, 16), 512, 0, stream>>>(f, r);
  }
  for (int s = 1; s < 8; ++s) {
    f16* hprev = (s & 1) ? h1p0 : h1p1;
    f16* hcur  = (s & 1) ? h1p1 : h1p0;
    ConvDir f{seq0 + (long)s * SLAB, SB, hprev, HB, wt1f, b1f, c1f, c1f, hcur, HB};
    conv_mfma<64, 32, 104, 6, 6, 32, 32, true, 128, 2, 2>
        <<<dim3(32, 1, 16), 512, 0, stream>>>(f, f);
  }

  // 5) final conv: concat(h1p1, h1bw) -> d_out f32 NCHW [B][64][64][64]
  {
    ConvDir f{h1p1, HB, h1bw, HB, wtfc, fcb, nullptr, (float*)d_out, nullptr, 0};
    conv_mfma<32, 32, 72, 4, 4, 32, 32, false, 64, 4, 1>
        <<<dim3(32, 1, 16), 512, 0, stream>>>(f, f);
  }
}

// Round 5
// 499.412 us; speedup vs baseline: 7.7501x; 1.0346x over previous
//
#include <hip/hip_runtime.h>

typedef _Float16 f16;
typedef _Float16 f16x8 __attribute__((ext_vector_type(8)));
typedef float f32x16 __attribute__((ext_vector_type(16)));

namespace {

constexpr int B_ = 16, T_ = 8, HW = 4096;

__device__ __forceinline__ float sigm(float x)  { return 1.f / (1.f + __expf(-x)); }
__device__ __forceinline__ float ftanh(float x) { return 1.f - 2.f / (1.f + __expf(2.f * x)); }

__device__ __forceinline__ f32x16 zero16() {
  f32x16 v;
#pragma unroll
  for (int i = 0; i < 16; ++i) v[i] = 0.f;
  return v;
}

__device__ __forceinline__ f16x8 zero8h() {
  f16x8 v;
#pragma unroll
  for (int i = 0; i < 8; ++i) v[i] = (f16)0.f;
  return v;
}

// ---------------- weight arrangement ----------------
// src OIHW f32 [NCO][CIN][3][3] -> dst f16 [dydx][kc][co][16]  (k16-contiguous per co)
struct WSet { const float* src; f16* dst; int KC, NCO, CIN; };

__global__ void warr_kernel(WSet s0, WSet s1, WSet s2, WSet s3, WSet s4) {
  WSet s = s0;
  switch (blockIdx.y) { case 1: s = s1; break; case 2: s = s2; break;
                        case 3: s = s3; break; case 4: s = s4; break; default: break; }
  int n = 9 * s.KC * s.NCO * 16;
  int i = blockIdx.x * 256 + threadIdx.x;
  if (i >= n) return;
  int kk = i & 15;
  int t = i >> 4;
  int co = t % s.NCO;
  int dkc = t / s.NCO;
  int kc = dkc % s.KC, dydx = dkc / s.KC;
  int ci = kc * 16 + kk;
  float v = (ci < s.CIN) ? s.src[(co * s.CIN + ci) * 9 + dydx] : 0.f;
  s.dst[i] = (f16)v;
}

// ---------------- positional encoding + add, NHWC f16 out ----------------
// xs layout: [B*T][4096][16] f16
__global__ void pe_kernel(const float* __restrict__ xa, const float* __restrict__ midi,
                          const float* __restrict__ w1, const float* __restrict__ b1,
                          const float* __restrict__ w2, const float* __restrict__ b2,
                          f16* __restrict__ xs) {
  int gid = blockIdx.x * 256 + threadIdx.x;   // one 16B unit (8 channels)
  int half = gid & 1;
  int gpx = gid >> 1;                         // (bt, pixel)
  int bt = gpx >> 12, gp = gpx & 4095;
  float n0 = -0.5f + midi[bt * 2 + 0] * (1.f / 64.f);
  float n1 = -0.5f + midi[bt * 2 + 1] * (1.f / 64.f);
  float hk[4];
#pragma unroll
  for (int k = 0; k < 4; ++k)
    hk[k] = fmaxf(fmaf(n0, w1[k], fmaf(n1, w1[4 + k], b1[k])), 0.f);
  f16x8 ov;
#pragma unroll
  for (int j = 0; j < 8; ++j) {
    int c = half * 8 + j;
    long p = (long)c * HW + gp;
    float z = b2[p];
#pragma unroll
    for (int k = 0; k < 4; ++k) z = fmaf(hk[k], w2[(long)k * 65536 + p], z);
    ov[j] = (f16)(xa[(long)bt * 65536 + p] + ftanh(z));
  }
  *reinterpret_cast<f16x8*>(xs + (long)gpx * 16 + half * 8) = ov;
}

// ---------------- MFMA conv / ConvLSTM step ----------------
// Tile: 128 pixels (8 rows x 16 cols), N = NCO. 8 waves = MG m-groups x NG n-groups, NF=1.
// Software-pipelined over NPH = 9*KC/CH phases: bf (global) prefetch depth 2,
// af (LDS) prefetch depth 1, fully unrolled -> static buffer indices.
struct ConvDir {
  const f16* x;  long xbs;   // batch stride (elements)
  const f16* h;  long hbs;
  const f16* w;
  const float* bias;
  const float* cin;
  float* cout;               // c-state out, or final f32 output for !GATES
  f16* hout; long hobs;
};

template<int CIN1, int CIN2, int CINPAD, int KCF, int KC, int CH, int HST, int HOST,
         bool GATES, int NCO, int MG, int MFRAG>
__global__ __launch_bounds__(512, 4)
void conv_mfma(ConvDir p0, ConvDir p1)
{
  constexpr int NG = 8 / MG;               // n-groups; NCO == NG*32
  constexpr int NCH = KC / CH;             // k-chunks per dydx
  constexpr int NPH = 9 * NCH;             // pipeline phases
  constexpr int ACT_BYTES = 180 * CINPAD * 2;
  constexpr int ZB_BYTES  = GATES ? 128 * 128 * 2 : 0;   // f16 z-buffer
  constexpr int SMEM = ACT_BYTES > ZB_BYTES ? ACT_BYTES : ZB_BYTES;
  __shared__ __align__(16) char smem[SMEM];
  f16* act = (f16*)smem;
  f16* zls = (f16*)smem;

  const ConvDir P = blockIdx.y ? p1 : p0;
  const int b = blockIdx.z;
  const int tileY = blockIdx.x >> 2, tileX = blockIdx.x & 3;
  const int gy0 = tileY * 8, gx0 = tileX * 16;
  const int tid = threadIdx.x;

  const int lane = tid & 63, wv = tid >> 6;   // wv in [0,8)
  const int mg = wv % MG, ng = wv / MG;
  const int rl = lane & 31;
  const int khalf = (lane >> 5) * 8;
  const int laneA = ((rl >> 4) * 18 + (rl & 15)) * CINPAD + khalf;   // f16 units
  const int laneB = rl * 16 + khalf;                                  // f16 units
  const f16* __restrict__ wng = P.w + laneB + (long)ng * 32 * 16;
  const f16* __restrict__ arow = act + laneA;

  // ---- staging: load phase (all loads issued back-to-back), then write phase ----
  constexpr int UPX = CIN1 / 8, UPH = CIN2 / 8, UPP = UPX + UPH;
  constexpr int NU  = 180 * UPP;
  constexpr int PER = (NU + 511) / 512;
  const bool have_h = (P.h != nullptr);
  f16x8 sreg[PER];
#pragma unroll
  for (int p = 0; p < PER; ++p) {
    sreg[p] = zero8h();
    int i = tid + p * 512;
    if (i < NU) {
      int px = i / UPP, u = i - px * UPP;
      int py = px / 18, pxx = px - py * 18;
      int gy = gy0 + py - 1, gx = gx0 + pxx - 1;
      if ((unsigned)gy < 64u && (unsigned)gx < 64u && (u < UPX || have_h)) {
        long gp = (long)gy * 64 + gx;
        const f16* src = (u < UPX) ? (P.x + b * P.xbs + gp * CIN1 + u * 8)
                                   : (P.h + b * P.hbs + gp * HST + (u - UPX) * 8);
        sreg[p] = *reinterpret_cast<const f16x8*>(src);
      }
    }
  }

  // ---- pipeline buffers ----
  f16x8 bfr[2][CH];
  f16x8 afr[2][MFRAG][CH];

  auto LBF = [&](int ph) {
    const int slot = ph & 1;
    const int dydx = ph / NCH, kc0 = (ph % NCH) * CH;
#pragma unroll
    for (int c = 0; c < CH; ++c)
      bfr[slot][c] = *reinterpret_cast<const f16x8*>(
          wng + (long)(dydx * KCF + kc0 + c) * NCO * 16);
  };
  auto LAF = [&](int ph) {
    const int slot = ph & 1;
    const int dydx = ph / NCH, kc0 = (ph % NCH) * CH;
    const int dy = dydx / 3, dx = dydx % 3;
#pragma unroll
    for (int m = 0; m < MFRAG; ++m)
#pragma unroll
      for (int c = 0; c < CH; ++c)
        afr[slot][m][c] = *reinterpret_cast<const f16x8*>(
            arow + dx * CINPAD + (((mg * MFRAG + m) * 2 + dy) * 18) * CINPAD
            + (kc0 + c) * 16);
  };

  // prefetch first two phases of weights while staging loads are in flight
  LBF(0);
  if (NPH > 1) LBF(1);

  // staging write phase
#pragma unroll
  for (int p = 0; p < PER; ++p) {
    int i = tid + p * 512;
    if (i < NU) {
      int px = i / UPP, u = i - px * UPP;
      *reinterpret_cast<f16x8*>(act + px * CINPAD + u * 8) = sreg[p];
    }
  }
  __syncthreads();

  f32x16 acc[MFRAG];
#pragma unroll
  for (int m = 0; m < MFRAG; ++m) acc[m] = zero16();

  LAF(0);
#pragma unroll
  for (int ph = 0; ph < NPH; ++ph) {
    const int slot = ph & 1;
    if (ph + 1 < NPH) LAF(ph + 1);
#pragma unroll
    for (int c = 0; c < CH; ++c)
#pragma unroll
      for (int m = 0; m < MFRAG; ++m)
        acc[m] = __builtin_amdgcn_mfma_f32_32x32x16_f16(afr[slot][m][c], bfr[slot][c], acc[m], 0, 0, 0);
    if (ph + 2 < NPH) LBF(ph + 2);
  }

  __syncthreads();

  if constexpr (GATES) {
    // phase A: write pre-activation z (f16) to zls[128 px][128 co]
    const int col = ng * 32 + rl;
    const float bs = P.bias[col];
#pragma unroll
    for (int m = 0; m < MFRAG; ++m) {
#pragma unroll
      for (int r = 0; r < 16; ++r) {
        int row = (r & 3) + 8 * (r >> 2) + 4 * (lane >> 5);
        int px = (mg * MFRAG + m) * 32 + row;
        zls[px * 128 + col] = (f16)(acc[m][r] + bs);
      }
    }
    __syncthreads();
    // phase B: gates -> c,h  (4096 (px,hid) pairs over 512 threads)
#pragma unroll
    for (int i = 0; i < 8; ++i) {
      int idx = tid + i * 512;
      int hid = idx & 31, px = idx >> 5;
      float zi = (float)zls[px * 128 + hid];
      float zf = (float)zls[px * 128 + 32 + hid];
      float zo = (float)zls[px * 128 + 64 + hid];
      float zg = (float)zls[px * 128 + 96 + hid];
      int py = px >> 4, pxx = px & 15;
      long gp = (long)(gy0 + py) * 64 + (gx0 + pxx);
      long cidx = ((long)b * HW + gp) * 32 + hid;
      float cp = P.cin ? P.cin[cidx] : 0.f;
      float c2 = sigm(zf) * cp + sigm(zi) * ftanh(zg);
      P.cout[cidx] = c2;
      P.hout[b * P.hobs + gp * HOST + hid] = (f16)(sigm(zo) * ftanh(c2));
    }
  } else {
    // final conv: direct f32 NCHW store (P.cout = output)
    const int co = ng * 32 + rl;
    const float bs = P.bias[co];
#pragma unroll
    for (int m = 0; m < MFRAG; ++m) {
#pragma unroll
      for (int r = 0; r < 16; ++r) {
        int row = (r & 3) + 8 * (r >> 2) + 4 * (lane >> 5);
        int pxt = (mg * MFRAG + m) * 32 + row;
        int py = pxt >> 4, pxx = pxt & 15;
        long gp = (long)(gy0 + py) * 64 + (gx0 + pxx);
        P.cout[((long)b * NCO + co) * HW + gp] = acc[m][r] + bs;
      }
    }
  }
}

} // namespace

extern "C" void kernel_launch(void* const* d_in, const int* in_sizes, int n_in,
                              void* d_out, int out_size, void* d_ws, size_t ws_size,
                              hipStream_t stream) {
  const float* x_audio = (const float*)d_in[0];
  const float* midi    = (const float*)d_in[1];
  const float* enc_w1  = (const float*)d_in[2];
  const float* enc_b1  = (const float*)d_in[3];
  const float* enc_w2  = (const float*)d_in[4];
  const float* enc_b2  = (const float*)d_in[5];
  const float* w0f = (const float*)d_in[6];
  const float* b0f = (const float*)d_in[7];
  const float* w0b = (const float*)d_in[8];
  const float* b0b = (const float*)d_in[9];
  const float* w1f = (const float*)d_in[10];
  const float* b1f = (const float*)d_in[11];
  const float* w1b = (const float*)d_in[12];
  const float* b1b = (const float*)d_in[13];
  const float* fcw = (const float*)d_in[14];
  const float* fcb = (const float*)d_in[15];

  char* ws = (char*)d_ws;
  size_t off = 0;
  auto alloc = [&](size_t bytes) { char* p = ws + off; off += (bytes + 255) & ~(size_t)255; return p; };

  f16* xs    = (f16*)alloc((size_t)B_ * T_ * HW * 16 * 2);   // [B*T][4096][16]
  f16* seq0  = (f16*)alloc((size_t)T_ * B_ * HW * 64 * 2);   // [T][B][4096][64]
  float* c0f = (float*)alloc((size_t)B_ * HW * 32 * 4);
  float* c0b = (float*)alloc((size_t)B_ * HW * 32 * 4);
  float* c1f = (float*)alloc((size_t)B_ * HW * 32 * 4);
  float* c1bw= (float*)alloc((size_t)B_ * HW * 32 * 4);
  f16* h1p0  = (f16*)alloc((size_t)B_ * HW * 32 * 2);
  f16* h1p1  = (f16*)alloc((size_t)B_ * HW * 32 * 2);
  f16* h1bw  = (f16*)alloc((size_t)B_ * HW * 32 * 2);
  f16* wt0f  = (f16*)alloc((size_t)9 * 3 * 128 * 16 * 2);
  f16* wt0b  = (f16*)alloc((size_t)9 * 3 * 128 * 16 * 2);
  f16* wt1f  = (f16*)alloc((size_t)9 * 6 * 128 * 16 * 2);
  f16* wt1b  = (f16*)alloc((size_t)9 * 6 * 128 * 16 * 2);
  f16* wtfc  = (f16*)alloc((size_t)9 * 4 * 64 * 16 * 2);

  // 1) arrange weights (5 sets, one launch)
  {
    WSet s0{w0f, wt0f, 3, 128, 48}, s1{w0b, wt0b, 3, 128, 48};
    WSet s2{w1f, wt1f, 6, 128, 96}, s3{w1b, wt1b, 6, 128, 96};
    WSet s4{fcw, wtfc, 4, 64, 64};
    warr_kernel<<<dim3(432, 5), 256, 0, stream>>>(s0, s1, s2, s3, s4);
  }

  // 2) positional encoding -> xs (NHWC f16)
  pe_kernel<<<(B_ * T_ * HW * 2) / 256, 256, 0, stream>>>(
      x_audio, midi, enc_w1, enc_b1, enc_w2, enc_b2, xs);

  const long XSB  = (long)T_ * HW * 16;   // xs batch stride
  const long SLAB = (long)B_ * HW * 64;   // seq0 time slab
  const long SB   = (long)HW * 64;        // seq0 batch stride
  const long HB   = (long)HW * 32;        // 32-ch batch stride

  // 3) layer 0, fwd + bwd merged per step
  {
    // step 0: no h, K = 16 ch (KC=1, CH=1)
    ConvDir f{xs, XSB, nullptr, SB, wt0f, b0f, nullptr, c0f, seq0, SB};
    ConvDir r{xs + (long)7 * HW * 16, XSB, nullptr, SB, wt0b, b0b, nullptr, c0b,
              seq0 + (long)7 * SLAB + 32, SB};
    conv_mfma<16, 32, 56, 3, 1, 1, 64, 64, true, 128, 2, 2>
        <<<dim3(32, 2, 16), 512, 0, stream>>>(f, r);
  }
  for (int s = 1; s < 8; ++s) {
    int tf = s, tb = 7 - s;
    ConvDir f{xs + (long)tf * HW * 16, XSB,
              seq0 + (long)(tf - 1) * SLAB, SB,
              wt0f, b0f, c0f, c0f,
              seq0 + (long)tf * SLAB, SB};
    ConvDir r{xs + (long)tb * HW * 16, XSB,
              seq0 + (long)(tb + 1) * SLAB + 32, SB,
              wt0b, b0b, c0b, c0b,
              seq0 + (long)tb * SLAB + 32, SB};
    conv_mfma<16, 32, 56, 3, 3, 3, 64, 64, true, 128, 2, 2>
        <<<dim3(32, 2, 16), 512, 0, stream>>>(f, r);
  }

  // 4) layer 1: step 0 fwd merged with the single needed bwd step (t=7, zero state)
  {
    ConvDir f{seq0, SB, nullptr, HB, wt1f, b1f, nullptr, c1f, h1p0, HB};
    ConvDir r{seq0 + 7 * SLAB, SB, nullptr, HB, wt1b, b1b, nullptr, c1bw, h1bw, HB};
    conv_mfma<64, 32, 104, 6, 4, 2, 32, 32, true, 128, 2, 2>
        <<<dim3(32, 2, 16), 512, 0, stream>>>(f, r);
  }
  for (int s = 1; s < 8; ++s) {
    f16* hprev = (s & 1) ? h1p0 : h1p1;
    f16* hcur  = (s & 1) ? h1p1 : h1p0;
    ConvDir f{seq0 + (long)s * SLAB, SB, hprev, HB, wt1f, b1f, c1f, c1f, hcur, HB};
    conv_mfma<64, 32, 104, 6, 6, 3, 32, 32, true, 128, 2, 2>
        <<<dim3(32, 1, 16), 512, 0, stream>>>(f, f);
  }

  // 5) final conv: concat(h1p1, h1bw) -> d_out f32 NCHW [B][64][64][64]
  {
    ConvDir f{h1p1, HB, h1bw, HB, wtfc, fcb, nullptr, (float*)d_out, nullptr, 0};
    conv_mfma<32, 32, 72, 4, 4, 2, 32, 32, false, 64, 4, 1>
        <<<dim3(32, 1, 16), 512, 0, stream>>>(f, f);
  }
}

// Round 6
// 490.620 us; speedup vs baseline: 7.8890x; 1.0179x over previous
//
#include <hip/hip_runtime.h>

typedef _Float16 f16;
typedef _Float16 f16x8 __attribute__((ext_vector_type(8)));
typedef float f32x16 __attribute__((ext_vector_type(16)));

namespace {

constexpr int B_ = 16, T_ = 8, HW = 4096;

__device__ __forceinline__ float sigm(float x)  { return 1.f / (1.f + __expf(-x)); }
__device__ __forceinline__ float ftanh(float x) { return 1.f - 2.f / (1.f + __expf(2.f * x)); }

__device__ __forceinline__ f32x16 zero16() {
  f32x16 v;
#pragma unroll
  for (int i = 0; i < 16; ++i) v[i] = 0.f;
  return v;
}

__device__ __forceinline__ f16x8 zero8h() {
  f16x8 v;
#pragma unroll
  for (int i = 0; i < 8; ++i) v[i] = (f16)0.f;
  return v;
}

// ---------------- weight arrangement ----------------
// src OIHW f32 [NCO][CIN][3][3] -> dst f16 [dydx][kc][co][16]  (k16-contiguous per co)
struct WSet { const float* src; f16* dst; int KC, NCO, CIN; };

__global__ void warr_kernel(WSet s0, WSet s1, WSet s2, WSet s3, WSet s4) {
  WSet s = s0;
  switch (blockIdx.y) { case 1: s = s1; break; case 2: s = s2; break;
                        case 3: s = s3; break; case 4: s = s4; break; default: break; }
  int n = 9 * s.KC * s.NCO * 16;
  int i = blockIdx.x * 256 + threadIdx.x;
  if (i >= n) return;
  int kk = i & 15;
  int t = i >> 4;
  int co = t % s.NCO;
  int dkc = t / s.NCO;
  int kc = dkc % s.KC, dydx = dkc / s.KC;
  int ci = kc * 16 + kk;
  float v = (ci < s.CIN) ? s.src[(co * s.CIN + ci) * 9 + dydx] : 0.f;
  s.dst[i] = (f16)v;
}

// ---------------- positional encoding + add, NHWC f16 out ----------------
// xs layout: [B*T][4096][16] f16
__global__ void pe_kernel(const float* __restrict__ xa, const float* __restrict__ midi,
                          const float* __restrict__ w1, const float* __restrict__ b1,
                          const float* __restrict__ w2, const float* __restrict__ b2,
                          f16* __restrict__ xs) {
  int gid = blockIdx.x * 256 + threadIdx.x;   // one 16B unit (8 channels)
  int half = gid & 1;
  int gpx = gid >> 1;                         // (bt, pixel)
  int bt = gpx >> 12, gp = gpx & 4095;
  float n0 = -0.5f + midi[bt * 2 + 0] * (1.f / 64.f);
  float n1 = -0.5f + midi[bt * 2 + 1] * (1.f / 64.f);
  float hk[4];
#pragma unroll
  for (int k = 0; k < 4; ++k)
    hk[k] = fmaxf(fmaf(n0, w1[k], fmaf(n1, w1[4 + k], b1[k])), 0.f);
  f16x8 ov;
#pragma unroll
  for (int j = 0; j < 8; ++j) {
    int c = half * 8 + j;
    long p = (long)c * HW + gp;
    float z = b2[p];
#pragma unroll
    for (int k = 0; k < 4; ++k) z = fmaf(hk[k], w2[(long)k * 65536 + p], z);
    ov[j] = (f16)(xa[(long)bt * 65536 + p] + ftanh(z));
  }
  *reinterpret_cast<f16x8*>(xs + (long)gpx * 16 + half * 8) = ov;
}

// ---------------- MFMA conv / ConvLSTM step ----------------
// Tile: 128 pixels (8 rows x 16 cols). 8 waves = MG(4) m-groups x NG(2) n-groups.
// MFRAG=1, NF = NCO/(NG*32): af (LDS) fragment reused across NF MFMAs.
// Pipelined over NPH = 9*KC phases (CH=1): bf prefetch depth 2, af depth 1.
struct ConvDir {
  const f16* x;  long xbs;   // batch stride (elements)
  const f16* h;  long hbs;
  const f16* w;
  const float* bias;
  const f16* cin;            // f16 c-state in (nullptr => zeros)
  f16* cout;                 // f16 c-state out (nullptr => skip write)
  float* fout;               // !GATES: final f32 NCHW output
  f16* hout; long hobs;
};

template<int CIN1, int CIN2, int CINPAD, int KCF, int KC, int HST, int HOST,
         bool GATES, int NCO, int MG>
__global__ __launch_bounds__(512, 4)
void conv_mfma(ConvDir p0, ConvDir p1)
{
  constexpr int NG = 8 / MG;               // n-groups
  constexpr int NF = NCO / (NG * 32);      // n-frags per wave
  constexpr int NPH = 9 * KC;              // pipeline phases (CH=1)
  constexpr int ACT_BYTES = 180 * CINPAD * 2;
  constexpr int ZB_BYTES  = GATES ? 128 * 128 * 2 : 0;   // f16 z-buffer [px][4*32]
  constexpr int SMEM = ACT_BYTES > ZB_BYTES ? ACT_BYTES : ZB_BYTES;
  __shared__ __align__(16) char smem[SMEM];
  f16* act = (f16*)smem;
  f16* zls = (f16*)smem;

  const ConvDir P = blockIdx.y ? p1 : p0;
  const int b = blockIdx.z;
  const int tileY = blockIdx.x >> 2, tileX = blockIdx.x & 3;
  const int gy0 = tileY * 8, gx0 = tileX * 16;
  const int tid = threadIdx.x;

  const int lane = tid & 63, wv = tid >> 6;   // wv in [0,8)
  const int mg = wv % MG, ng = wv / MG;
  const int rl = lane & 31;
  const int khalf = (lane >> 5) * 8;
  const int laneA = ((rl >> 4) * 18 + (rl & 15)) * CINPAD + khalf;   // f16 units
  const int laneB = rl * 16 + khalf;                                  // f16 units
  const f16* __restrict__ wng = P.w + laneB + (long)ng * NF * 32 * 16;
  const f16* __restrict__ arow = act + laneA;

  // ---- staging: load phase (all loads issued back-to-back), then write phase ----
  constexpr int UPX = CIN1 / 8, UPH = CIN2 / 8, UPP = UPX + UPH;
  constexpr int NU  = 180 * UPP;
  constexpr int PER = (NU + 511) / 512;
  const bool have_h = (P.h != nullptr);
  f16x8 sreg[PER];
#pragma unroll
  for (int p = 0; p < PER; ++p) {
    sreg[p] = zero8h();
    int i = tid + p * 512;
    if (i < NU) {
      int px = i / UPP, u = i - px * UPP;
      int py = px / 18, pxx = px - py * 18;
      int gy = gy0 + py - 1, gx = gx0 + pxx - 1;
      if ((unsigned)gy < 64u && (unsigned)gx < 64u && (u < UPX || have_h)) {
        long gp = (long)gy * 64 + gx;
        const f16* src = (u < UPX) ? (P.x + b * P.xbs + gp * CIN1 + u * 8)
                                   : (P.h + b * P.hbs + gp * HST + (u - UPX) * 8);
        sreg[p] = *reinterpret_cast<const f16x8*>(src);
      }
    }
  }

  // ---- pipeline buffers (CH=1) ----
  f16x8 bfr[2][NF];
  f16x8 afr[2];

  auto LBF = [&](int ph) {
    const int slot = ph & 1;
    const int dydx = ph / KC, kc = ph % KC;
#pragma unroll
    for (int nf = 0; nf < NF; ++nf)
      bfr[slot][nf] = *reinterpret_cast<const f16x8*>(
          wng + ((long)(dydx * KCF + kc) * NCO + nf * 32) * 16);
  };
  auto LAF = [&](int ph) {
    const int slot = ph & 1;
    const int dydx = ph / KC, kc = ph % KC;
    const int dy = dydx / 3, dx = dydx % 3;
    afr[slot] = *reinterpret_cast<const f16x8*>(
        arow + dx * CINPAD + ((mg * 2 + dy) * 18) * CINPAD + kc * 16);
  };

  // prefetch first two phases of weights while staging loads are in flight
  LBF(0);
  if (NPH > 1) LBF(1);

  // staging write phase
#pragma unroll
  for (int p = 0; p < PER; ++p) {
    int i = tid + p * 512;
    if (i < NU) {
      int px = i / UPP, u = i - px * UPP;
      *reinterpret_cast<f16x8*>(act + px * CINPAD + u * 8) = sreg[p];
    }
  }
  __syncthreads();

  f32x16 acc[NF];
#pragma unroll
  for (int nf = 0; nf < NF; ++nf) acc[nf] = zero16();

  LAF(0);
#pragma unroll
  for (int ph = 0; ph < NPH; ++ph) {
    const int slot = ph & 1;
    if (ph + 1 < NPH) LAF(ph + 1);
#pragma unroll
    for (int nf = 0; nf < NF; ++nf)
      acc[nf] = __builtin_amdgcn_mfma_f32_32x32x16_f16(afr[slot], bfr[slot][nf], acc[nf], 0, 0, 0);
    if (ph + 2 < NPH) LBF(ph + 2);
  }

  __syncthreads();

  if constexpr (GATES) {
    // phase A (single, all waves disjoint): write z (f16) to zls[128 px][128 co]
#pragma unroll
    for (int nf = 0; nf < NF; ++nf) {
      const int col = (ng * NF + nf) * 32 + rl;
      const float bs = P.bias[col];
#pragma unroll
      for (int r = 0; r < 16; ++r) {
        int row = (r & 3) + 8 * (r >> 2) + 4 * (lane >> 5);
        zls[(mg * 32 + row) * 128 + col] = (f16)(acc[nf][r] + bs);
      }
    }
    __syncthreads();
    // phase B: vectorized gates; thread -> (px = tid>>2, hid chunk q = tid&3)
    const int q = tid & 3, px = tid >> 2;
    const int py = px >> 4, pxx = px & 15;
    const long gp = (long)(gy0 + py) * 64 + (gx0 + pxx);
    const f16* zb = zls + px * 128 + q * 8;
    f16x8 zi8 = *reinterpret_cast<const f16x8*>(zb);
    f16x8 zf8 = *reinterpret_cast<const f16x8*>(zb + 32);
    f16x8 zo8 = *reinterpret_cast<const f16x8*>(zb + 64);
    f16x8 zg8 = *reinterpret_cast<const f16x8*>(zb + 96);
    const long cbase = ((long)b * HW + gp) * 32 + q * 8;
    f16x8 c8 = P.cin ? *reinterpret_cast<const f16x8*>(P.cin + cbase) : zero8h();
    f16x8 c2v, h2v;
#pragma unroll
    for (int j = 0; j < 8; ++j) {
      float c2 = sigm((float)zf8[j]) * (float)c8[j]
               + sigm((float)zi8[j]) * ftanh((float)zg8[j]);
      c2v[j] = (f16)c2;
      h2v[j] = (f16)(sigm((float)zo8[j]) * ftanh(c2));
    }
    if (P.cout) *reinterpret_cast<f16x8*>(P.cout + cbase) = c2v;
    *reinterpret_cast<f16x8*>(P.hout + b * P.hobs + gp * HOST + q * 8) = h2v;
  } else {
    // final conv: direct f32 NCHW store
#pragma unroll
    for (int nf = 0; nf < NF; ++nf) {
      const int co = (ng * NF + nf) * 32 + rl;
      const float bs = P.bias[co];
#pragma unroll
      for (int r = 0; r < 16; ++r) {
        int row = (r & 3) + 8 * (r >> 2) + 4 * (lane >> 5);
        int pxt = mg * 32 + row;
        int py = pxt >> 4, pxx = pxt & 15;
        long gp = (long)(gy0 + py) * 64 + (gx0 + pxx);
        P.fout[((long)b * NCO + co) * HW + gp] = acc[nf][r] + bs;
      }
    }
  }
}

} // namespace

extern "C" void kernel_launch(void* const* d_in, const int* in_sizes, int n_in,
                              void* d_out, int out_size, void* d_ws, size_t ws_size,
                              hipStream_t stream) {
  const float* x_audio = (const float*)d_in[0];
  const float* midi    = (const float*)d_in[1];
  const float* enc_w1  = (const float*)d_in[2];
  const float* enc_b1  = (const float*)d_in[3];
  const float* enc_w2  = (const float*)d_in[4];
  const float* enc_b2  = (const float*)d_in[5];
  const float* w0f = (const float*)d_in[6];
  const float* b0f = (const float*)d_in[7];
  const float* w0b = (const float*)d_in[8];
  const float* b0b = (const float*)d_in[9];
  const float* w1f = (const float*)d_in[10];
  const float* b1f = (const float*)d_in[11];
  const float* w1b = (const float*)d_in[12];
  const float* b1b = (const float*)d_in[13];
  const float* fcw = (const float*)d_in[14];
  const float* fcb = (const float*)d_in[15];

  char* ws = (char*)d_ws;
  size_t off = 0;
  auto alloc = [&](size_t bytes) { char* p = ws + off; off += (bytes + 255) & ~(size_t)255; return p; };

  f16* xs    = (f16*)alloc((size_t)B_ * T_ * HW * 16 * 2);   // [B*T][4096][16]
  f16* seq0  = (f16*)alloc((size_t)T_ * B_ * HW * 64 * 2);   // [T][B][4096][64]
  f16* c0f   = (f16*)alloc((size_t)B_ * HW * 32 * 2);
  f16* c0b   = (f16*)alloc((size_t)B_ * HW * 32 * 2);
  f16* c1f   = (f16*)alloc((size_t)B_ * HW * 32 * 2);
  f16* h1p0  = (f16*)alloc((size_t)B_ * HW * 32 * 2);
  f16* h1p1  = (f16*)alloc((size_t)B_ * HW * 32 * 2);
  f16* h1bw  = (f16*)alloc((size_t)B_ * HW * 32 * 2);
  f16* wt0f  = (f16*)alloc((size_t)9 * 3 * 128 * 16 * 2);
  f16* wt0b  = (f16*)alloc((size_t)9 * 3 * 128 * 16 * 2);
  f16* wt1f  = (f16*)alloc((size_t)9 * 6 * 128 * 16 * 2);
  f16* wt1b  = (f16*)alloc((size_t)9 * 6 * 128 * 16 * 2);
  f16* wtfc  = (f16*)alloc((size_t)9 * 4 * 64 * 16 * 2);

  // 1) arrange weights (5 sets, one launch)
  {
    WSet s0{w0f, wt0f, 3, 128, 48}, s1{w0b, wt0b, 3, 128, 48};
    WSet s2{w1f, wt1f, 6, 128, 96}, s3{w1b, wt1b, 6, 128, 96};
    WSet s4{fcw, wtfc, 4, 64, 64};
    warr_kernel<<<dim3(432, 5), 256, 0, stream>>>(s0, s1, s2, s3, s4);
  }

  // 2) positional encoding -> xs (NHWC f16)
  pe_kernel<<<(B_ * T_ * HW * 2) / 256, 256, 0, stream>>>(
      x_audio, midi, enc_w1, enc_b1, enc_w2, enc_b2, xs);

  const long XSB  = (long)T_ * HW * 16;   // xs batch stride
  const long SLAB = (long)B_ * HW * 64;   // seq0 time slab
  const long SB   = (long)HW * 64;        // seq0 batch stride
  const long HB   = (long)HW * 32;        // 32-ch batch stride

  // 3) layer 0, fwd + bwd merged per step
  {
    // step 0: no h, K = 16 ch (KC=1)
    ConvDir f{xs, XSB, nullptr, SB, wt0f, b0f, nullptr, c0f, nullptr, seq0, SB};
    ConvDir r{xs + (long)7 * HW * 16, XSB, nullptr, SB, wt0b, b0b, nullptr, c0b,
              nullptr, seq0 + (long)7 * SLAB + 32, SB};
    conv_mfma<16, 32, 56, 3, 1, 64, 64, true, 128, 4>
        <<<dim3(32, 2, 16), 512, 0, stream>>>(f, r);
  }
  for (int s = 1; s < 8; ++s) {
    int tf = s, tb = 7 - s;
    ConvDir f{xs + (long)tf * HW * 16, XSB,
              seq0 + (long)(tf - 1) * SLAB, SB,
              wt0f, b0f, c0f, (s == 7) ? nullptr : c0f, nullptr,
              seq0 + (long)tf * SLAB, SB};
    ConvDir r{xs + (long)tb * HW * 16, XSB,
              seq0 + (long)(tb + 1) * SLAB + 32, SB,
              wt0b, b0b, c0b, (s == 7) ? nullptr : c0b, nullptr,
              seq0 + (long)tb * SLAB + 32, SB};
    conv_mfma<16, 32, 56, 3, 3, 64, 64, true, 128, 4>
        <<<dim3(32, 2, 16), 512, 0, stream>>>(f, r);
  }

  // 4) layer 1: step 0 fwd merged with the single needed bwd step (t=7, zero state)
  {
    ConvDir f{seq0, SB, nullptr, HB, wt1f, b1f, nullptr, c1f, nullptr, h1p0, HB};
    ConvDir r{seq0 + 7 * SLAB, SB, nullptr, HB, wt1b, b1b, nullptr, nullptr, nullptr, h1bw, HB};
    conv_mfma<64, 32, 104, 6, 4, 32, 32, true, 128, 4>
        <<<dim3(32, 2, 16), 512, 0, stream>>>(f, r);
  }
  for (int s = 1; s < 8; ++s) {
    f16* hprev = (s & 1) ? h1p0 : h1p1;
    f16* hcur  = (s & 1) ? h1p1 : h1p0;
    ConvDir f{seq0 + (long)s * SLAB, SB, hprev, HB, wt1f, b1f,
              c1f, (s == 7) ? nullptr : c1f, nullptr, hcur, HB};
    conv_mfma<64, 32, 104, 6, 6, 32, 32, true, 128, 4>
        <<<dim3(32, 1, 16), 512, 0, stream>>>(f, f);
  }

  // 5) final conv: concat(h1p1, h1bw) -> d_out f32 NCHW [B][64][64][64]
  {
    ConvDir f{h1p1, HB, h1bw, HB, wtfc, fcb, nullptr, nullptr, (float*)d_out, nullptr, 0};
    conv_mfma<32, 32, 72, 4, 4, 32, 32, false, 64, 4>
        <<<dim3(32, 1, 16), 512, 0, stream>>>(f, f);
  }
}

// Round 7
// 462.788 us; speedup vs baseline: 8.3634x; 1.0601x over previous
//
#include <hip/hip_runtime.h>

typedef _Float16 f16;
typedef _Float16 f16x8 __attribute__((ext_vector_type(8)));
typedef float f32x16 __attribute__((ext_vector_type(16)));

namespace {

constexpr int B_ = 16, T_ = 8, HW = 4096;

__device__ __forceinline__ float sigm(float x)  { return 1.f / (1.f + __expf(-x)); }
__device__ __forceinline__ float ftanh(float x) { return 1.f - 2.f / (1.f + __expf(2.f * x)); }

__device__ __forceinline__ f32x16 zero16() {
  f32x16 v;
#pragma unroll
  for (int i = 0; i < 16; ++i) v[i] = 0.f;
  return v;
}

__device__ __forceinline__ f16x8 zero8h() {
  f16x8 v;
#pragma unroll
  for (int i = 0; i < 8; ++i) v[i] = (f16)0.f;
  return v;
}

// ---------------- weight arrangement ----------------
// src OIHW f32 [NCO][CIN][3][3] -> dst f16 [dydx][kc][co][16]  (k16-contiguous per co)
struct WSet { const float* src; f16* dst; int KC, NCO, CIN; };

__global__ void warr_kernel(WSet s0, WSet s1, WSet s2, WSet s3, WSet s4) {
  WSet s = s0;
  switch (blockIdx.y) { case 1: s = s1; break; case 2: s = s2; break;
                        case 3: s = s3; break; case 4: s = s4; break; default: break; }
  int n = 9 * s.KC * s.NCO * 16;
  int i = blockIdx.x * 256 + threadIdx.x;
  if (i >= n) return;
  int kk = i & 15;
  int t = i >> 4;
  int co = t % s.NCO;
  int dkc = t / s.NCO;
  int kc = dkc % s.KC, dydx = dkc / s.KC;
  int ci = kc * 16 + kk;
  float v = (ci < s.CIN) ? s.src[(co * s.CIN + ci) * 9 + dydx] : 0.f;
  s.dst[i] = (f16)v;
}

// ---------------- positional encoding + add, NHWC f16 out ----------------
// xs layout: [B*T][4096][16] f16
__global__ void pe_kernel(const float* __restrict__ xa, const float* __restrict__ midi,
                          const float* __restrict__ w1, const float* __restrict__ b1,
                          const float* __restrict__ w2, const float* __restrict__ b2,
                          f16* __restrict__ xs) {
  int gid = blockIdx.x * 256 + threadIdx.x;   // one 16B unit (8 channels)
  int half = gid & 1;
  int gpx = gid >> 1;                         // (bt, pixel)
  int bt = gpx >> 12, gp = gpx & 4095;
  float n0 = -0.5f + midi[bt * 2 + 0] * (1.f / 64.f);
  float n1 = -0.5f + midi[bt * 2 + 1] * (1.f / 64.f);
  float hk[4];
#pragma unroll
  for (int k = 0; k < 4; ++k)
    hk[k] = fmaxf(fmaf(n0, w1[k], fmaf(n1, w1[4 + k], b1[k])), 0.f);
  f16x8 ov;
#pragma unroll
  for (int j = 0; j < 8; ++j) {
    int c = half * 8 + j;
    long p = (long)c * HW + gp;
    float z = b2[p];
#pragma unroll
    for (int k = 0; k < 4; ++k) z = fmaf(hk[k], w2[(long)k * 65536 + p], z);
    ov[j] = (f16)(xa[(long)bt * 65536 + p] + ftanh(z));
  }
  *reinterpret_cast<f16x8*>(xs + (long)gpx * 16 + half * 8) = ov;
}

// ---------------- MFMA conv / ConvLSTM step ----------------
// Tile: 128 pixels (8 rows x 16 cols). 4 waves = 2 m-groups x 2 n-groups.
// Wave tile: MFRAG=2 m-frags x NF n-frags -> each B-frag (global) feeds MFRAG
// MFMAs, each A-frag (LDS) feeds NF MFMAs. bf prefetch depth 3, af depth 2.
struct ConvDir {
  const f16* x;  long xbs;   // batch stride (elements)
  const f16* h;  long hbs;
  const f16* w;
  const float* bias;
  const f16* cin;            // f16 c-state in (nullptr => zeros)
  f16* cout;                 // f16 c-state out (nullptr => skip write)
  float* fout;               // !GATES: final f32 NCHW output
  f16* hout; long hobs;
};

template<int CIN1, int CIN2, int CINPAD, int KCF, int KC, int HST, int HOST,
         bool GATES, int NCO>
__global__ __launch_bounds__(256, 2)
void conv_mfma(ConvDir p0, ConvDir p1)
{
  constexpr int MFRAG = 2;                 // m-frags per wave
  constexpr int NF = NCO / 64;             // n-frags per wave (NG=2)
  constexpr int NPH = 9 * KC;              // pipeline phases (CH=1)
  constexpr int ACT_BYTES = 180 * CINPAD * 2;
  constexpr int ZB_BYTES  = GATES ? 128 * 128 * 2 : 0;   // f16 z-buffer [px][4*32]
  constexpr int SMEM = ACT_BYTES > ZB_BYTES ? ACT_BYTES : ZB_BYTES;
  __shared__ __align__(16) char smem[SMEM];
  f16* act = (f16*)smem;
  f16* zls = (f16*)smem;

  const ConvDir P = blockIdx.y ? p1 : p0;
  const int b = blockIdx.z;
  const int tileY = blockIdx.x >> 2, tileX = blockIdx.x & 3;
  const int gy0 = tileY * 8, gx0 = tileX * 16;
  const int tid = threadIdx.x;

  const int lane = tid & 63, wv = tid >> 6;   // wv in [0,4)
  const int mg = wv & 1, ng = wv >> 1;
  const int rl = lane & 31;
  const int khalf = (lane >> 5) * 8;
  const int laneA = ((rl >> 4) * 18 + (rl & 15)) * CINPAD + khalf;   // f16 units
  const int laneB = rl * 16 + khalf;                                  // f16 units
  const f16* __restrict__ wng = P.w + laneB + (long)ng * NF * 32 * 16;
  const f16* __restrict__ arow = act + laneA;

  // ---- staging: load phase (all loads issued back-to-back), then write phase ----
  constexpr int UPX = CIN1 / 8, UPH = CIN2 / 8, UPP = UPX + UPH;
  constexpr int NU  = 180 * UPP;
  constexpr int PER = (NU + 255) / 256;
  const bool have_h = (P.h != nullptr);
  f16x8 sreg[PER];
#pragma unroll
  for (int p = 0; p < PER; ++p) {
    sreg[p] = zero8h();
    int i = tid + p * 256;
    if (i < NU) {
      int px = i / UPP, u = i - px * UPP;
      int py = px / 18, pxx = px - py * 18;
      int gy = gy0 + py - 1, gx = gx0 + pxx - 1;
      if ((unsigned)gy < 64u && (unsigned)gx < 64u && (u < UPX || have_h)) {
        long gp = (long)gy * 64 + gx;
        const f16* src = (u < UPX) ? (P.x + b * P.xbs + gp * CIN1 + u * 8)
                                   : (P.h + b * P.hbs + gp * HST + (u - UPX) * 8);
        sreg[p] = *reinterpret_cast<const f16x8*>(src);
      }
    }
  }

  // ---- pipeline buffers ----
  f16x8 bfr[3][NF];
  f16x8 afr[2][MFRAG];

  auto LBF = [&](int ph) {
    const int slot = ph % 3;
    const int dydx = ph / KC, kc = ph % KC;
#pragma unroll
    for (int nf = 0; nf < NF; ++nf)
      bfr[slot][nf] = *reinterpret_cast<const f16x8*>(
          wng + ((long)(dydx * KCF + kc) * NCO + nf * 32) * 16);
  };
  auto LAF = [&](int ph) {
    const int slot = ph & 1;
    const int dydx = ph / KC, kc = ph % KC;
    const int dy = dydx / 3, dx = dydx % 3;
#pragma unroll
    for (int m = 0; m < MFRAG; ++m)
      afr[slot][m] = *reinterpret_cast<const f16x8*>(
          arow + dx * CINPAD + (((mg * MFRAG + m) * 2 + dy) * 18) * CINPAD + kc * 16);
  };

  // prefetch first two weight phases while staging loads are in flight
  LBF(0);
  if (NPH > 1) LBF(1);

  // staging write phase
#pragma unroll
  for (int p = 0; p < PER; ++p) {
    int i = tid + p * 256;
    if (i < NU) {
      int px = i / UPP, u = i - px * UPP;
      *reinterpret_cast<f16x8*>(act + px * CINPAD + u * 8) = sreg[p];
    }
  }
  __syncthreads();

  if (NPH > 2) LBF(2);

  f32x16 acc[MFRAG][NF];
#pragma unroll
  for (int m = 0; m < MFRAG; ++m)
#pragma unroll
    for (int nf = 0; nf < NF; ++nf) acc[m][nf] = zero16();

  LAF(0);
#pragma unroll
  for (int ph = 0; ph < NPH; ++ph) {
    if (ph + 1 < NPH) LAF(ph + 1);
#pragma unroll
    for (int m = 0; m < MFRAG; ++m)
#pragma unroll
      for (int nf = 0; nf < NF; ++nf)
        acc[m][nf] = __builtin_amdgcn_mfma_f32_32x32x16_f16(
            afr[ph & 1][m], bfr[ph % 3][nf], acc[m][nf], 0, 0, 0);
    if (ph + 3 < NPH) LBF(ph + 3);
  }

  __syncthreads();

  if constexpr (GATES) {
    // phase A (single, all waves disjoint): write z (f16) to zls[128 px][128 co]
#pragma unroll
    for (int m = 0; m < MFRAG; ++m) {
#pragma unroll
      for (int nf = 0; nf < NF; ++nf) {
        const int col = (ng * NF + nf) * 32 + rl;
        const float bs = P.bias[col];
#pragma unroll
        for (int r = 0; r < 16; ++r) {
          int row = (r & 3) + 8 * (r >> 2) + 4 * (lane >> 5);
          int px = (mg * MFRAG + m) * 32 + row;
          zls[px * 128 + col] = (f16)(acc[m][nf][r] + bs);
        }
      }
    }
    __syncthreads();
    // phase B: vectorized gates; item -> (px = idx>>2, hid chunk q = idx&3)
#pragma unroll
    for (int it = 0; it < 2; ++it) {
      const int idx = tid + it * 256;
      const int q = idx & 3, px = idx >> 2;
      const int py = px >> 4, pxx = px & 15;
      const long gp = (long)(gy0 + py) * 64 + (gx0 + pxx);
      const f16* zb = zls + px * 128 + q * 8;
      f16x8 zi8 = *reinterpret_cast<const f16x8*>(zb);
      f16x8 zf8 = *reinterpret_cast<const f16x8*>(zb + 32);
      f16x8 zo8 = *reinterpret_cast<const f16x8*>(zb + 64);
      f16x8 zg8 = *reinterpret_cast<const f16x8*>(zb + 96);
      const long cbase = ((long)b * HW + gp) * 32 + q * 8;
      f16x8 c8 = P.cin ? *reinterpret_cast<const f16x8*>(P.cin + cbase) : zero8h();
      f16x8 c2v, h2v;
#pragma unroll
      for (int j = 0; j < 8; ++j) {
        float c2 = sigm((float)zf8[j]) * (float)c8[j]
                 + sigm((float)zi8[j]) * ftanh((float)zg8[j]);
        c2v[j] = (f16)c2;
        h2v[j] = (f16)(sigm((float)zo8[j]) * ftanh(c2));
      }
      if (P.cout) *reinterpret_cast<f16x8*>(P.cout + cbase) = c2v;
      *reinterpret_cast<f16x8*>(P.hout + b * P.hobs + gp * HOST + q * 8) = h2v;
    }
  } else {
    // final conv: direct f32 NCHW store
#pragma unroll
    for (int m = 0; m < MFRAG; ++m) {
#pragma unroll
      for (int nf = 0; nf < NF; ++nf) {
        const int co = (ng * NF + nf) * 32 + rl;
        const float bs = P.bias[co];
#pragma unroll
        for (int r = 0; r < 16; ++r) {
          int row = (r & 3) + 8 * (r >> 2) + 4 * (lane >> 5);
          int pxt = (mg * MFRAG + m) * 32 + row;
          int py = pxt >> 4, pxx = pxt & 15;
          long gp = (long)(gy0 + py) * 64 + (gx0 + pxx);
          P.fout[((long)b * NCO + co) * HW + gp] = acc[m][nf][r] + bs;
        }
      }
    }
  }
}

} // namespace

extern "C" void kernel_launch(void* const* d_in, const int* in_sizes, int n_in,
                              void* d_out, int out_size, void* d_ws, size_t ws_size,
                              hipStream_t stream) {
  const float* x_audio = (const float*)d_in[0];
  const float* midi    = (const float*)d_in[1];
  const float* enc_w1  = (const float*)d_in[2];
  const float* enc_b1  = (const float*)d_in[3];
  const float* enc_w2  = (const float*)d_in[4];
  const float* enc_b2  = (const float*)d_in[5];
  const float* w0f = (const float*)d_in[6];
  const float* b0f = (const float*)d_in[7];
  const float* w0b = (const float*)d_in[8];
  const float* b0b = (const float*)d_in[9];
  const float* w1f = (const float*)d_in[10];
  const float* b1f = (const float*)d_in[11];
  const float* w1b = (const float*)d_in[12];
  const float* b1b = (const float*)d_in[13];
  const float* fcw = (const float*)d_in[14];
  const float* fcb = (const float*)d_in[15];

  char* ws = (char*)d_ws;
  size_t off = 0;
  auto alloc = [&](size_t bytes) { char* p = ws + off; off += (bytes + 255) & ~(size_t)255; return p; };

  f16* xs    = (f16*)alloc((size_t)B_ * T_ * HW * 16 * 2);   // [B*T][4096][16]
  f16* seq0  = (f16*)alloc((size_t)T_ * B_ * HW * 64 * 2);   // [T][B][4096][64]
  f16* c0f   = (f16*)alloc((size_t)B_ * HW * 32 * 2);
  f16* c0b   = (f16*)alloc((size_t)B_ * HW * 32 * 2);
  f16* c1f   = (f16*)alloc((size_t)B_ * HW * 32 * 2);
  f16* h1p0  = (f16*)alloc((size_t)B_ * HW * 32 * 2);
  f16* h1p1  = (f16*)alloc((size_t)B_ * HW * 32 * 2);
  f16* h1bw  = (f16*)alloc((size_t)B_ * HW * 32 * 2);
  f16* wt0f  = (f16*)alloc((size_t)9 * 3 * 128 * 16 * 2);
  f16* wt0b  = (f16*)alloc((size_t)9 * 3 * 128 * 16 * 2);
  f16* wt1f  = (f16*)alloc((size_t)9 * 6 * 128 * 16 * 2);
  f16* wt1b  = (f16*)alloc((size_t)9 * 6 * 128 * 16 * 2);
  f16* wtfc  = (f16*)alloc((size_t)9 * 4 * 64 * 16 * 2);

  // 1) arrange weights (5 sets, one launch)
  {
    WSet s0{w0f, wt0f, 3, 128, 48}, s1{w0b, wt0b, 3, 128, 48};
    WSet s2{w1f, wt1f, 6, 128, 96}, s3{w1b, wt1b, 6, 128, 96};
    WSet s4{fcw, wtfc, 4, 64, 64};
    warr_kernel<<<dim3(432, 5), 256, 0, stream>>>(s0, s1, s2, s3, s4);
  }

  // 2) positional encoding -> xs (NHWC f16)
  pe_kernel<<<(B_ * T_ * HW * 2) / 256, 256, 0, stream>>>(
      x_audio, midi, enc_w1, enc_b1, enc_w2, enc_b2, xs);

  const long XSB  = (long)T_ * HW * 16;   // xs batch stride
  const long SLAB = (long)B_ * HW * 64;   // seq0 time slab
  const long SB   = (long)HW * 64;        // seq0 batch stride
  const long HB   = (long)HW * 32;        // 32-ch batch stride

  dim3 blk(256);

  // 3) layer 0, fwd + bwd merged per step
  {
    // step 0: no h, K = 16 ch (KC=1)
    ConvDir f{xs, XSB, nullptr, SB, wt0f, b0f, nullptr, c0f, nullptr, seq0, SB};
    ConvDir r{xs + (long)7 * HW * 16, XSB, nullptr, SB, wt0b, b0b, nullptr, c0b,
              nullptr, seq0 + (long)7 * SLAB + 32, SB};
    conv_mfma<16, 32, 56, 3, 1, 64, 64, true, 128>
        <<<dim3(32, 2, 16), blk, 0, stream>>>(f, r);
  }
  for (int s = 1; s < 8; ++s) {
    int tf = s, tb = 7 - s;
    ConvDir f{xs + (long)tf * HW * 16, XSB,
              seq0 + (long)(tf - 1) * SLAB, SB,
              wt0f, b0f, c0f, (s == 7) ? nullptr : c0f, nullptr,
              seq0 + (long)tf * SLAB, SB};
    ConvDir r{xs + (long)tb * HW * 16, XSB,
              seq0 + (long)(tb + 1) * SLAB + 32, SB,
              wt0b, b0b, c0b, (s == 7) ? nullptr : c0b, nullptr,
              seq0 + (long)tb * SLAB + 32, SB};
    conv_mfma<16, 32, 56, 3, 3, 64, 64, true, 128>
        <<<dim3(32, 2, 16), blk, 0, stream>>>(f, r);
  }

  // 4) layer 1: step 0 fwd merged with the single needed bwd step (t=7, zero state)
  {
    ConvDir f{seq0, SB, nullptr, HB, wt1f, b1f, nullptr, c1f, nullptr, h1p0, HB};
    ConvDir r{seq0 + 7 * SLAB, SB, nullptr, HB, wt1b, b1b, nullptr, nullptr, nullptr, h1bw, HB};
    conv_mfma<64, 32, 104, 6, 4, 32, 32, true, 128>
        <<<dim3(32, 2, 16), blk, 0, stream>>>(f, r);
  }
  for (int s = 1; s < 8; ++s) {
    f16* hprev = (s & 1) ? h1p0 : h1p1;
    f16* hcur  = (s & 1) ? h1p1 : h1p0;
    ConvDir f{seq0 + (long)s * SLAB, SB, hprev, HB, wt1f, b1f,
              c1f, (s == 7) ? nullptr : c1f, nullptr, hcur, HB};
    conv_mfma<64, 32, 104, 6, 6, 32, 32, true, 128>
        <<<dim3(32, 1, 16), blk, 0, stream>>>(f, f);
  }

  // 5) final conv: concat(h1p1, h1bw) -> d_out f32 NCHW [B][64][64][64]
  {
    ConvDir f{h1p1, HB, h1bw, HB, wtfc, fcb, nullptr, nullptr, (float*)d_out, nullptr, 0};
    conv_mfma<32, 32, 72, 4, 4, 32, 32, false, 64>
        <<<dim3(32, 1, 16), blk, 0, stream>>>(f, f);
  }
}